// Round 13
// baseline (500.817 us; speedup 1.0000x reference)
//
#include <hip/hip_runtime.h>
#include <hip/hip_fp16.h>

// RGCN 3-layer, transform-first with column-split passes:
//   Y = A @ [W_0..W_7, W_root] restricted to output cols [p*PW,(p+1)*PW)
//   h[n, cols] = relu( Y[rootblk][n] + sum_e (1/cnt[n,ty]) * Y[ty][src_e] + bias )
// Y is BLOCKED BY RELATION-CHUNK: Y[9][N][PW] -> GEMM stores are contiguous
// 16KB streams per block (vs 256B @ 1152B stride row-major = DRAM-page thrash).
// Edge sort: bucket pipeline (bucket = 256 dst nodes). sinvp precomputed.
// Edge pass: 16-lane subgroups, f16x4 vector gather, shfl sinv broadcast.
// GEMM: grid (m-tiles, 2); A staged once -> registers; swapped MFMA ->
// f16x4 LDS repack -> coalesced f16x8 blocked stores.
// Layer-2 pruned to marked nodes; layer 3 at roots only.

typedef _Float16 f16;
typedef _Float16 f16x2 __attribute__((ext_vector_type(2)));
typedef _Float16 f16x4 __attribute__((ext_vector_type(4)));
typedef _Float16 f16x8 __attribute__((ext_vector_type(8)));
typedef float f32x4 __attribute__((ext_vector_type(4)));

#define NREL 8
#define ACHUNK 8192

// ---------------- fallback setup kernels (N > 131072 only) ----------------
__global__ void k_hist(const int* __restrict__ dst, int E, int* __restrict__ cnt) {
  int e = blockIdx.x * 256 + threadIdx.x;
  if (e < E) atomicAdd(&cnt[dst[e]], 1);
}

__global__ void k_scan1(const int* __restrict__ in, int* __restrict__ out,
                        int* __restrict__ part, int n) {
  __shared__ int sh[256];
  int b = blockIdx.x, t = threadIdx.x;
  int base = b * 4096 + t * 16;
  int v[16]; int s = 0;
#pragma unroll
  for (int j = 0; j < 16; j++) { int idx = base + j; int x = (idx < n) ? in[idx] : 0; v[j] = s; s += x; }
  sh[t] = s; __syncthreads();
  for (int off = 1; off < 256; off <<= 1) {
    int x = 0; if (t >= off) x = sh[t - off];
    __syncthreads();
    if (t >= off) sh[t] += x;
    __syncthreads();
  }
  int excl = (t == 0) ? 0 : sh[t - 1];
  if (t == 255) part[b] = sh[255];
#pragma unroll
  for (int j = 0; j < 16; j++) { int idx = base + j; if (idx < n) out[idx] = v[j] + excl; }
}

__global__ void k_scan2(int* __restrict__ part, int nb) {
  __shared__ int sh[256];
  int t = threadIdx.x;
  sh[t] = (t < nb) ? part[t] : 0; __syncthreads();
  for (int off = 1; off < 256; off <<= 1) {
    int x = 0; if (t >= off) x = sh[t - off];
    __syncthreads();
    if (t >= off) sh[t] += x;
    __syncthreads();
  }
  if (t < nb) part[t] = (t == 0) ? 0 : sh[t - 1];
}

__global__ void k_scan3(int* __restrict__ out, const int* __restrict__ part, int n) {
  int i = blockIdx.x * 256 + threadIdx.x;
  if (i < n) out[i] += part[i >> 12];
}

__global__ void k_scatter(const int* __restrict__ src, const int* __restrict__ dstv,
                          const int* __restrict__ et, int E,
                          const int* __restrict__ off, int* __restrict__ fill,
                          int* __restrict__ sps) {
  int e = blockIdx.x * 256 + threadIdx.x;
  if (e >= E) return;
  int d = dstv[e];
  int pos = off[d] + atomicAdd(&fill[d], 1);
  sps[pos] = src[e] | (et[e] << 20);
}

__global__ void k_sentinel(int* __restrict__ p, int v) { *p = v; }

// ---------------- bucket pipeline (bucket = 256 consecutive dst nodes) ----------
__global__ __launch_bounds__(256) void k_bhist(const int* __restrict__ dstv, int E,
                                               int* __restrict__ bcnt, int nbuck) {
  __shared__ int h[512];
  int t = threadIdx.x;
  for (int i = t; i < 512; i += 256) h[i] = 0;
  __syncthreads();
  int lo = blockIdx.x * ACHUNK;
  int hi = lo + ACHUNK < E ? lo + ACHUNK : E;
  for (int e = lo + t; e < hi; e += 256) atomicAdd(&h[dstv[e] >> 8], 1);
  __syncthreads();
  for (int i = t; i < nbuck; i += 256)
    if (h[i]) atomicAdd(&bcnt[i], h[i]);
}

__global__ __launch_bounds__(512) void k_bscan(const int* __restrict__ bcnt,
                                               int* __restrict__ boff, int nbuck) {
  __shared__ int sh[512];
  int t = threadIdx.x;
  sh[t] = (t < nbuck) ? bcnt[t] : 0;
  __syncthreads();
  for (int o = 1; o < 512; o <<= 1) {
    int v = 0; if (t >= o) v = sh[t - o];
    __syncthreads();
    sh[t] += v;
    __syncthreads();
  }
  if (t <= nbuck && t < 512) boff[t] = (t == 0) ? 0 : sh[t - 1];
  if (t == 511 && nbuck >= 512) boff[nbuck] = sh[511];
}

__global__ __launch_bounds__(256) void k_bucketA(
    const int* __restrict__ src, const int* __restrict__ dstv,
    const int* __restrict__ et, int E, const int* __restrict__ boff,
    int* __restrict__ bfill, int* __restrict__ tmp, int nbuck) {
  __shared__ int hist[512];
  __shared__ int base[512];
  int t = threadIdx.x;
  int lo = blockIdx.x * ACHUNK;
  int hi = lo + ACHUNK < E ? lo + ACHUNK : E;
  for (int i = t; i < nbuck; i += 256) hist[i] = 0;
  __syncthreads();
  for (int e = lo + t; e < hi; e += 256)
    atomicAdd(&hist[dstv[e] >> 8], 1);
  __syncthreads();
  for (int i = t; i < nbuck; i += 256) {
    int c = hist[i];
    base[i] = c ? (boff[i] + atomicAdd(&bfill[i], c)) : 0;
  }
  __syncthreads();
  for (int e = lo + t; e < hi; e += 256) {
    int d = dstv[e];
    int b = d >> 8;
    int pos = atomicAdd(&base[b], 1);
    tmp[pos] = src[e] | (et[e] << 20) | ((d & 255) << 23);
  }
}

__global__ __launch_bounds__(256) void k_bucketB2(const int* __restrict__ tmp,
                                                  const int* __restrict__ boff,
                                                  int* __restrict__ off,
                                                  int* __restrict__ sps, int N) {
  __shared__ int cnt[256];
  __shared__ int sh[256];
  __shared__ int loff[257];
  int b = blockIdx.x, t = threadIdx.x;
  int n0 = b << 8;
  int nn = (N - n0) < 256 ? (N - n0) : 256;
  cnt[t] = 0;
  __syncthreads();
  int e0 = boff[b], e1 = boff[b + 1];
  for (int e = e0 + t; e < e1; e += 256)
    atomicAdd(&cnt[(tmp[e] >> 23) & 255], 1);
  __syncthreads();
  sh[t] = cnt[t];
  __syncthreads();
  for (int o = 1; o < 256; o <<= 1) {
    int v = 0; if (t >= o) v = sh[t - o];
    __syncthreads();
    sh[t] += v;
    __syncthreads();
  }
  loff[t] = (t == 0) ? 0 : sh[t - 1];
  if (t == 255) loff[256] = sh[255];
  __syncthreads();
  if (t < nn) off[n0 + t] = e0 + loff[t];
  cnt[t] = 0;   // reuse as fill
  __syncthreads();
  for (int e = e0 + t; e < e1; e += 256) {
    int v = tmp[e];
    int dl = (v >> 23) & 255;
    int pos = e0 + loff[dl] + atomicAdd(&cnt[dl], 1);
    sps[pos] = v & 0x7FFFFF;
  }
}

// mark nodes whose h2 is read by layer 3: roots + src of root in-edges
__global__ void k_mark(const int* __restrict__ ridx, const int* __restrict__ off,
                       const int* __restrict__ sps, int* __restrict__ mark) {
  int i = blockIdx.x, t = threadIdx.x;
  int n = ridx[i];
  if (t == 0) mark[n] = 1;
  int e0 = off[n], e1 = off[n + 1];
  for (int e = e0 + t; e < e1; e += 64) mark[sps[e] & 0xFFFFF] = 1;
}

// precompute per-(node,type) inverse counts
__global__ __launch_bounds__(256) void k_sinvp(const int* __restrict__ sps,
                                               const int* __restrict__ off,
                                               float* __restrict__ sinvp, int N) {
  __shared__ int c[16][8];
  int t = threadIdx.x;
  int g = t >> 4, st = t & 15;
  int n = blockIdx.x * 16 + g;
  if (st < 8) c[g][st] = 0;
  __syncthreads();
  if (n < N) {
    int e0 = off[n], e1 = off[n + 1];
    for (int e = e0 + st; e < e1; e += 16)
      atomicAdd(&c[g][((unsigned)sps[e]) >> 20], 1);
  }
  __syncthreads();
  if (n < N && st < 8) {
    int cc = c[g][st];
    sinvp[n * 8 + st] = 1.0f / (float)(cc > 1 ? cc : 1);
  }
}

__global__ void k_f32_to_f16(const float* __restrict__ in, f16* __restrict__ out, int n4) {
  int i = blockIdx.x * 256 + threadIdx.x;
  if (i < n4) {
    float4 v = ((const float4*)in)[i];
    f16x4 o; o[0] = (f16)v.x; o[1] = (f16)v.y; o[2] = (f16)v.z; o[3] = (f16)v.w;
    ((f16x4*)out)[i] = o;
  }
}

// weights for pass p: Wt[row][k], row = cb*PW + j -> source col p*PW+j of chunk cb
__global__ void k_tpw(const float* __restrict__ wrel, const float* __restrict__ wroot,
                      f16* __restrict__ dst, int PW, int p) {
  int row = blockIdx.x, k = threadIdx.x;
  float v = 0.f;
  if (row < 9 * PW) {
    int cb = row / PW, j = row - cb * PW;
    int col = p * PW + j;
    v = (cb < 8) ? wrel[(size_t)cb * 16384 + k * 128 + col] : wroot[k * 128 + col];
  }
  dst[(size_t)row * 128 + k] = (f16)v;
}

// ---------------- GEMM: Y[9][M][PW] = blocked(A[M x 128] * Bt^T) ----------------
// grid (mb, 2): block handles col-tiles blockIdx.y, +gridDim.y, ...
// A staged once -> 16 reg fragments; As reused as repack buffer H. Swapped
// MFMA -> f16x4 LDS repack -> f16x8 stores into relation-blocked Y:
// col gc lands at Y[gc/PW][row][gc%PW] -> per block two contiguous 16KB runs.
__global__ __launch_bounds__(256) void k_gemm3(const f16* __restrict__ A,
                                               const f16* __restrict__ Bt,
                                               f16* __restrict__ Y, int M, int ncol) {
  __shared__ f16 As[128 * 136];
  int tid = threadIdx.x;
  int m0 = blockIdx.x * 128;
  int PW = ncol / 9;
  int cbs = (PW == 64) ? 6 : 5;
#pragma unroll
  for (int cch = 0; cch < 8; cch++) {
    int ci = tid + cch * 256;
    int row = ci >> 4, c8 = ci & 15;
    int gm = m0 + row;
    f16x8 va = {};
    if (gm < M) va = *(const f16x8*)(A + (size_t)gm * 128 + c8 * 8);
    *(f16x8*)(As + row * 136 + c8 * 8) = va;
  }
  __syncthreads();
  int wid = tid >> 6, lane = tid & 63;
  int wm = (wid & 1) * 64, wn = (wid >> 1) * 64;
  int lm = lane & 15, lk = lane >> 4;
  // A fragments to registers (4 ks x 4 i); As is then dead -> reuse as H
  f16x8 af[4][4];
#pragma unroll
  for (int ks = 0; ks < 4; ks++)
#pragma unroll
    for (int i = 0; i < 4; i++)
      af[ks][i] = *(const f16x8*)(As + (wm + i * 16 + lm) * 136 + ks * 32 + lk * 8);
  __syncthreads();
  f16* H = As;
  int NT = (ncol + 127) >> 7;
  for (int nt = blockIdx.y; nt < NT; nt += gridDim.y) {
    int n0 = nt * 128;
    f32x4 acc[4][4] = {};
#pragma unroll
    for (int ks = 0; ks < 4; ks++) {
      f16x8 b[4];
#pragma unroll
      for (int j = 0; j < 4; j++)
        b[j] = *(const f16x8*)(Bt + (size_t)(n0 + wn + j * 16 + lm) * 128 + ks * 32 + lk * 8);
#pragma unroll
      for (int i = 0; i < 4; i++)
#pragma unroll
        for (int j = 0; j < 4; j++)
          acc[i][j] = __builtin_amdgcn_mfma_f32_16x16x32_f16(b[j], af[ks][i], acc[i][j], 0, 0, 0);
    }
    // repack: lane owns row (wm+i*16+lm), cols (wn+j*16+lk*4 .. +3)
#pragma unroll
    for (int i = 0; i < 4; i++)
#pragma unroll
      for (int j = 0; j < 4; j++) {
        f16x4 o;
        o[0] = (f16)acc[i][j][0]; o[1] = (f16)acc[i][j][1];
        o[2] = (f16)acc[i][j][2]; o[3] = (f16)acc[i][j][3];
        *(f16x4*)(H + (wm + i * 16 + lm) * 136 + wn + j * 16 + lk * 4) = o;
      }
    __syncthreads();
    for (int i = tid; i < 128 * 16; i += 256) {
      int row = i >> 4, c8 = i & 15;
      int gm = m0 + row;
      int gc = n0 + c8 * 8;
      if (gm < M && gc < ncol) {
        int cb = gc >> cbs, wi = gc & (PW - 1);
        *(f16x8*)(Y + ((size_t)cb * M + gm) * PW + wi) =
            *(const f16x8*)(H + row * 136 + c8 * 8);
      }
    }
    __syncthreads();
  }
}

// ---------------- vectorized edge aggregation for one column pass ----------------
// Y is blocked [9][N][PW]; per edge reads contiguous f16x4 of Y[ty][src].
template <int PW>
__global__ __launch_bounds__(256) void k_edge_v(
    const f16* __restrict__ Y, const int* __restrict__ sps,
    const int* __restrict__ off, const float* __restrict__ sinvp,
    const float* __restrict__ bias, f16* __restrict__ hout,
    const int* __restrict__ mark, int N, int pass) {
  constexpr int CPL = PW / 16;
  int t = threadIdx.x;
  int g = t >> 4, st = t & 15;
  int n = blockIdx.x * 16 + g;
  if (n >= N) return;
  if (mark && !mark[n]) return;
  float sv = (st < 8) ? sinvp[n * 8 + st] : 0.f;
  int e0 = off[n], e1 = off[n + 1];
  float a[CPL], b2[CPL];
  {
    const f16* rp = Y + ((size_t)8 * N + n) * PW + st * CPL;
    const float* bp = bias + pass * PW + st * CPL;
#pragma unroll
    for (int q = 0; q < CPL; q++) { a[q] = (float)rp[q] + bp[q]; b2[q] = 0.f; }
  }
  int sgbase = t & 48;
  int e = e0;
  for (; e + 1 < e1; e += 2) {
    int p0 = sps[e], p1 = sps[e + 1];
    int s0 = p0 & 0xFFFFF, ty0 = ((unsigned)p0) >> 20;
    int s1 = p1 & 0xFFFFF, ty1 = ((unsigned)p1) >> 20;
    float sc0 = __shfl(sv, sgbase | ty0);
    float sc1 = __shfl(sv, sgbase | ty1);
    const f16* q0 = Y + ((size_t)ty0 * N + s0) * PW + st * CPL;
    const f16* q1 = Y + ((size_t)ty1 * N + s1) * PW + st * CPL;
    if constexpr (PW == 64) {
      f16x4 v0 = *(const f16x4*)q0;
      f16x4 v1 = *(const f16x4*)q1;
      a[0] += (float)v0[0] * sc0; a[1] += (float)v0[1] * sc0;
      a[2] += (float)v0[2] * sc0; a[3] += (float)v0[3] * sc0;
      b2[0] += (float)v1[0] * sc1; b2[1] += (float)v1[1] * sc1;
      b2[2] += (float)v1[2] * sc1; b2[3] += (float)v1[3] * sc1;
    } else {
      f16x2 v0 = *(const f16x2*)q0;
      f16x2 v1 = *(const f16x2*)q1;
      a[0] += (float)v0[0] * sc0; a[1] += (float)v0[1] * sc0;
      b2[0] += (float)v1[0] * sc1; b2[1] += (float)v1[1] * sc1;
    }
  }
  if (e < e1) {
    int p0 = sps[e];
    int s0 = p0 & 0xFFFFF, ty0 = ((unsigned)p0) >> 20;
    float sc0 = __shfl(sv, sgbase | ty0);
    const f16* q0 = Y + ((size_t)ty0 * N + s0) * PW + st * CPL;
    if constexpr (PW == 64) {
      f16x4 v0 = *(const f16x4*)q0;
      a[0] += (float)v0[0] * sc0; a[1] += (float)v0[1] * sc0;
      a[2] += (float)v0[2] * sc0; a[3] += (float)v0[3] * sc0;
    } else {
      f16x2 v0 = *(const f16x2*)q0;
      a[0] += (float)v0[0] * sc0; a[1] += (float)v0[1] * sc0;
    }
  }
  if constexpr (PW == 64) {
    f16x4 o;
#pragma unroll
    for (int q = 0; q < 4; q++) o[q] = (f16)fmaxf(a[q] + b2[q], 0.f);
    *(f16x4*)(hout + (size_t)n * 128 + pass * PW + st * 4) = o;
  } else {
    f16x2 o;
#pragma unroll
    for (int q = 0; q < 2; q++) o[q] = (f16)fmaxf(a[q] + b2[q], 0.f);
    *(f16x2*)(hout + (size_t)n * 128 + pass * PW + st * 2) = o;
  }
}

// ---------------- layer 3: only at root rows, weights in LDS ----------------
__global__ __launch_bounds__(128) void k_layer3(const f16* __restrict__ h2,
                                                const int* __restrict__ sps,
                                                const int* __restrict__ off,
                                                const float* __restrict__ sinvp,
                                                const int* __restrict__ ridx,
                                                const float* __restrict__ wrel,
                                                const float* __restrict__ wroot,
                                                const float* __restrict__ b3,
                                                float* __restrict__ out) {
  __shared__ f16 W[9 * 2048];
  __shared__ float red[2][16];
  __shared__ float sinv_s[8];
  int t = threadIdx.x;
  int n = ridx[blockIdx.x];
  for (int j = t; j < 9 * 2048; j += 128)
    W[j] = (f16)((j < 8 * 2048) ? wrel[j] : wroot[j - 8 * 2048]);
  if (t < 8) sinv_s[t] = sinvp[n * 8 + t];
  __syncthreads();
  int e0 = off[n], e1 = off[n + 1];
  int c = t & 15, kg = t >> 4;
  float a = 0.f;
  for (int e = e0; e < e1; e++) {
    int ps = sps[e];
    int s = ps & 0xFFFFF, ty = ((unsigned)ps) >> 20;
    float p = 0.f;
#pragma unroll
    for (int j = 0; j < 16; j++) {
      int k = kg * 16 + j;
      p += (float)h2[(size_t)s * 128 + k] * (float)W[ty * 2048 + k * 16 + c];
    }
    a += sinv_s[ty] * p;
  }
  {
    float p = 0.f;
#pragma unroll
    for (int j = 0; j < 16; j++) {
      int k = kg * 16 + j;
      p += (float)h2[(size_t)n * 128 + k] * (float)W[8 * 2048 + k * 16 + c];
    }
    a += p;
  }
  a += __shfl_xor(a, 16);
  a += __shfl_xor(a, 32);
  if ((t & 63) < 16) red[t >> 6][t & 15] = a;
  __syncthreads();
  if (t < 16) out[(size_t)blockIdx.x * 16 + t] = red[0][t] + red[1][t] + b3[t];
}

// ---------------- host ----------------
extern "C" void kernel_launch(void* const* d_in, const int* in_sizes, int n_in,
                              void* d_out, int out_size, void* d_ws, size_t ws_size,
                              hipStream_t stream) {
  const float* x     = (const float*)d_in[0];
  const int*   eidx  = (const int*)d_in[1];
  const int*   etyp  = (const int*)d_in[2];
  const int*   ridx  = (const int*)d_in[3];
  const float* wrel1 = (const float*)d_in[4];
  const float* root1 = (const float*)d_in[5];
  const float* b1    = (const float*)d_in[6];
  const float* wrel2 = (const float*)d_in[7];
  const float* root2 = (const float*)d_in[8];
  const float* b2    = (const float*)d_in[9];
  const float* wrel3 = (const float*)d_in[10];
  const float* root3 = (const float*)d_in[11];
  const float* b3    = (const float*)d_in[12];

  int N = in_sizes[0] / 128;
  int E = in_sizes[2];
  int NROOT = in_sizes[3];
  const int* esrc = eidx;
  const int* edst = eidx + E;

  char* p = (char*)d_ws;
  auto alloc = [&](size_t bytes) { void* r = (void*)p; p += (bytes + 255) & ~(size_t)255; return r; };
  int*   off   = (int*)alloc((size_t)(N + 1) * 4);
  int*   sps   = (int*)alloc((size_t)E * 4);
  f16*   h1    = (f16*)alloc((size_t)N * 128 * 2);
  f16*   h2    = (f16*)alloc((size_t)N * 128 * 2);   // also holds f16(x) for layer 1
  int*   mark  = (int*)alloc((size_t)N * 4);
  float* sinvp = (float*)alloc((size_t)N * 8 * 4);
  f16*   Wt    = (f16*)alloc((size_t)640 * 128 * 2);
  int*   bcnt  = (int*)alloc(512 * 4);
  int*   boff  = (int*)alloc(513 * 4);
  int*   bfill = (int*)alloc(512 * 4);

  size_t used = (size_t)(p - (char*)d_ws);
  size_t remain = ws_size > used ? ws_size - used : 0;
  int PW = (remain >= (size_t)N * 9 * 64 * 2 + (1u << 20)) ? 64 : 32;
  int ldy = 9 * PW;
  f16* Y = (f16*)alloc((size_t)N * ldy * 2);
  // setup-only scratch lives in Y's region (dead until first GEMM writes Y):
  int* tmp  = (int*)Y;             // E ints (phase-A bucket-grouped edges)
  int* part = tmp + E;             // 4096 ints (fallback scan partials)
  int* fill = part + 4096;         // N ints (fallback scatter only)

  int nbuck = (N + 255) >> 8;
  int nbA = (E + ACHUNK - 1) / ACHUNK;
  hipMemsetAsync(mark, 0, (size_t)N * 4, stream);

  if (nbuck <= 512) {
    hipMemsetAsync(bcnt, 0, 512 * 4, stream);
    hipMemsetAsync(bfill, 0, 512 * 4, stream);
    k_bhist<<<nbA, 256, 0, stream>>>(edst, E, bcnt, nbuck);
    k_bscan<<<1, 512, 0, stream>>>(bcnt, boff, nbuck);
    k_bucketA<<<nbA, 256, 0, stream>>>(esrc, edst, etyp, E, boff, bfill, tmp, nbuck);
    k_bucketB2<<<nbuck, 256, 0, stream>>>(tmp, boff, off, sps, N);
    k_sentinel<<<1, 1, 0, stream>>>(off + N, E);
  } else {
    int eb = (E + 255) / 256;
    hipMemsetAsync(off, 0, (size_t)(N + 1) * 4, stream);
    hipMemsetAsync(fill, 0, (size_t)N * 4, stream);
    k_hist<<<eb, 256, 0, stream>>>(edst, E, off);
    int nb1 = (N + 4095) / 4096;
    k_scan1<<<nb1, 256, 0, stream>>>(off, off, part, N);
    k_scan2<<<1, 256, 0, stream>>>(part, nb1);
    k_scan3<<<(N + 255) / 256, 256, 0, stream>>>(off, part, N);
    k_sentinel<<<1, 1, 0, stream>>>(off + N, E);
    k_scatter<<<eb, 256, 0, stream>>>(esrc, edst, etyp, E, off, fill, sps);
  }
  k_mark<<<NROOT, 64, 0, stream>>>(ridx, off, sps, mark);
  int ng16 = (N + 15) / 16;
  k_sinvp<<<ng16, 256, 0, stream>>>(sps, off, sinvp, N);
  k_f32_to_f16<<<((N * 32) + 255) / 256, 256, 0, stream>>>(x, h2, N * 32);

  int mb = (N + 127) / 128;
  int NT = (ldy + 127) / 128;
  int npass = 128 / PW;

  // layer 1: A = f16(x) (aliased in h2)
  for (int ps = 0; ps < npass; ps++) {
    k_tpw<<<NT * 128, 128, 0, stream>>>(wrel1, root1, Wt, PW, ps);
    k_gemm3<<<dim3(mb, 2), 256, 0, stream>>>(h2, Wt, Y, N, ldy);
    if (PW == 64)
      k_edge_v<64><<<ng16, 256, 0, stream>>>(Y, sps, off, sinvp, b1, h1, nullptr, N, ps);
    else
      k_edge_v<32><<<ng16, 256, 0, stream>>>(Y, sps, off, sinvp, b1, h1, nullptr, N, ps);
  }
  // layer 2: A = h1, edge pass pruned to marked nodes
  for (int ps = 0; ps < npass; ps++) {
    k_tpw<<<NT * 128, 128, 0, stream>>>(wrel2, root2, Wt, PW, ps);
    k_gemm3<<<dim3(mb, 2), 256, 0, stream>>>(h1, Wt, Y, N, ldy);
    if (PW == 64)
      k_edge_v<64><<<ng16, 256, 0, stream>>>(Y, sps, off, sinvp, b2, h2, mark, N, ps);
    else
      k_edge_v<32><<<ng16, 256, 0, stream>>>(Y, sps, off, sinvp, b2, h2, mark, N, ps);
  }
  k_layer3<<<NROOT, 128, 0, stream>>>(h2, sps, off, sinvp, ridx, wrel3, root3, b3,
                                      (float*)d_out);
}

// Round 14
// 476.032 us; speedup vs baseline: 1.0521x; 1.0521x over previous
//
#include <hip/hip_runtime.h>
#include <hip/hip_fp16.h>

// RGCN 3-layer, transform-first with column-split passes:
//   Y = A @ [W_0..W_7, W_root] restricted to output cols [p*PW,(p+1)*PW)
//   h[n, cols] = relu( Y[rootblk][n] + sum_e (1/cnt[n,ty]) * Y[ty][src_e] + bias )
// Y is blocked by relation-chunk: Y[9][N][PW]. Edge sort: bucket pipeline
// (bucket = 256 dst nodes); bucketB3 also emits off[] AND per-(node,type)
// inverse counts (sinvp) in one pass. All 4 weight tables built upfront (tpw4).
// Layer-1 GEMM reads fp32 x directly (templated staging) - no convert kernel.
// Edge pass: 16-lane subgroups, f16x4 vector gather, shfl sinv broadcast.
// GEMM: grid (m-tiles, 2); A staged once -> registers; swapped MFMA ->
// f16x4 LDS repack -> coalesced f16x8 blocked stores.
// Layer-2 pruned to marked nodes; layer 3 at roots only.

typedef _Float16 f16;
typedef _Float16 f16x2 __attribute__((ext_vector_type(2)));
typedef _Float16 f16x4 __attribute__((ext_vector_type(4)));
typedef _Float16 f16x8 __attribute__((ext_vector_type(8)));
typedef float f32x4 __attribute__((ext_vector_type(4)));

#define NREL 8
#define ACHUNK 8192
#define WTELEM (640 * 128)

// ---------------- fallback setup kernels (N > 131072 only) ----------------
__global__ void k_hist(const int* __restrict__ dst, int E, int* __restrict__ cnt) {
  int e = blockIdx.x * 256 + threadIdx.x;
  if (e < E) atomicAdd(&cnt[dst[e]], 1);
}

__global__ void k_scan1(const int* __restrict__ in, int* __restrict__ out,
                        int* __restrict__ part, int n) {
  __shared__ int sh[256];
  int b = blockIdx.x, t = threadIdx.x;
  int base = b * 4096 + t * 16;
  int v[16]; int s = 0;
#pragma unroll
  for (int j = 0; j < 16; j++) { int idx = base + j; int x = (idx < n) ? in[idx] : 0; v[j] = s; s += x; }
  sh[t] = s; __syncthreads();
  for (int off = 1; off < 256; off <<= 1) {
    int x = 0; if (t >= off) x = sh[t - off];
    __syncthreads();
    if (t >= off) sh[t] += x;
    __syncthreads();
  }
  int excl = (t == 0) ? 0 : sh[t - 1];
  if (t == 255) part[b] = sh[255];
#pragma unroll
  for (int j = 0; j < 16; j++) { int idx = base + j; if (idx < n) out[idx] = v[j] + excl; }
}

__global__ void k_scan2(int* __restrict__ part, int nb) {
  __shared__ int sh[256];
  int t = threadIdx.x;
  sh[t] = (t < nb) ? part[t] : 0; __syncthreads();
  for (int off = 1; off < 256; off <<= 1) {
    int x = 0; if (t >= off) x = sh[t - off];
    __syncthreads();
    if (t >= off) sh[t] += x;
    __syncthreads();
  }
  if (t < nb) part[t] = (t == 0) ? 0 : sh[t - 1];
}

__global__ void k_scan3(int* __restrict__ out, const int* __restrict__ part, int n) {
  int i = blockIdx.x * 256 + threadIdx.x;
  if (i < n) out[i] += part[i >> 12];
}

__global__ void k_scatter(const int* __restrict__ src, const int* __restrict__ dstv,
                          const int* __restrict__ et, int E,
                          const int* __restrict__ off, int* __restrict__ fill,
                          int* __restrict__ sps) {
  int e = blockIdx.x * 256 + threadIdx.x;
  if (e >= E) return;
  int d = dstv[e];
  int pos = off[d] + atomicAdd(&fill[d], 1);
  sps[pos] = src[e] | (et[e] << 20);
}

__global__ __launch_bounds__(256) void k_sinvp(const int* __restrict__ sps,
                                               const int* __restrict__ off,
                                               float* __restrict__ sinvp, int N) {
  __shared__ int c[16][8];
  int t = threadIdx.x;
  int g = t >> 4, st = t & 15;
  int n = blockIdx.x * 16 + g;
  if (st < 8) c[g][st] = 0;
  __syncthreads();
  if (n < N) {
    int e0 = off[n], e1 = off[n + 1];
    for (int e = e0 + st; e < e1; e += 16)
      atomicAdd(&c[g][((unsigned)sps[e]) >> 20], 1);
  }
  __syncthreads();
  if (n < N && st < 8) {
    int cc = c[g][st];
    sinvp[n * 8 + st] = 1.0f / (float)(cc > 1 ? cc : 1);
  }
}

__global__ void k_sentinel(int* __restrict__ p, int v) { *p = v; }

// ---------------- bucket pipeline (bucket = 256 consecutive dst nodes) ----------
__global__ __launch_bounds__(256) void k_bhist(const int* __restrict__ dstv, int E,
                                               int* __restrict__ bcnt, int nbuck) {
  __shared__ int h[512];
  int t = threadIdx.x;
  for (int i = t; i < 512; i += 256) h[i] = 0;
  __syncthreads();
  int lo = blockIdx.x * ACHUNK;
  int hi = lo + ACHUNK < E ? lo + ACHUNK : E;
  for (int e = lo + t; e < hi; e += 256) atomicAdd(&h[dstv[e] >> 8], 1);
  __syncthreads();
  for (int i = t; i < nbuck; i += 256)
    if (h[i]) atomicAdd(&bcnt[i], h[i]);
}

__global__ __launch_bounds__(512) void k_bscan(const int* __restrict__ bcnt,
                                               int* __restrict__ boff, int nbuck) {
  __shared__ int sh[512];
  int t = threadIdx.x;
  sh[t] = (t < nbuck) ? bcnt[t] : 0;
  __syncthreads();
  for (int o = 1; o < 512; o <<= 1) {
    int v = 0; if (t >= o) v = sh[t - o];
    __syncthreads();
    sh[t] += v;
    __syncthreads();
  }
  if (t <= nbuck && t < 512) boff[t] = (t == 0) ? 0 : sh[t - 1];
  if (t == 511 && nbuck >= 512) boff[nbuck] = sh[511];
}

__global__ __launch_bounds__(256) void k_bucketA(
    const int* __restrict__ src, const int* __restrict__ dstv,
    const int* __restrict__ et, int E, const int* __restrict__ boff,
    int* __restrict__ bfill, int* __restrict__ tmp, int nbuck) {
  __shared__ int hist[512];
  __shared__ int base[512];
  int t = threadIdx.x;
  int lo = blockIdx.x * ACHUNK;
  int hi = lo + ACHUNK < E ? lo + ACHUNK : E;
  for (int i = t; i < nbuck; i += 256) hist[i] = 0;
  __syncthreads();
  for (int e = lo + t; e < hi; e += 256)
    atomicAdd(&hist[dstv[e] >> 8], 1);
  __syncthreads();
  for (int i = t; i < nbuck; i += 256) {
    int c = hist[i];
    base[i] = c ? (boff[i] + atomicAdd(&bfill[i], c)) : 0;
  }
  __syncthreads();
  for (int e = lo + t; e < hi; e += 256) {
    int d = dstv[e];
    int b = d >> 8;
    int pos = atomicAdd(&base[b], 1);
    tmp[pos] = src[e] | (et[e] << 20) | ((d & 255) << 23);
  }
}

// Phase B: per-bucket (node,type) count -> off[] + sinvp[] + exact scatter
__global__ __launch_bounds__(256) void k_bucketB3(const int* __restrict__ tmp,
                                                  const int* __restrict__ boff,
                                                  int* __restrict__ off,
                                                  int* __restrict__ sps,
                                                  float* __restrict__ sinvp, int N) {
  __shared__ int cty[2048];    // per-(node,type) counts
  __shared__ int sh[256];
  __shared__ int loff[257];
  __shared__ int fill[256];
  int b = blockIdx.x, t = threadIdx.x;
  int n0 = b << 8;
  int nn = (N - n0) < 256 ? (N - n0) : 256;
#pragma unroll
  for (int j = 0; j < 8; j++) cty[t + j * 256] = 0;
  __syncthreads();
  int e0 = boff[b], e1 = boff[b + 1];
  for (int e = e0 + t; e < e1; e += 256) {
    int v = tmp[e];
    int dl = (v >> 23) & 255, ty = (v >> 20) & 7;
    atomicAdd(&cty[dl * 8 + ty], 1);
  }
  __syncthreads();
  {
    int c = 0;
#pragma unroll
    for (int j = 0; j < 8; j++) c += cty[t * 8 + j];
    sh[t] = c;
  }
  __syncthreads();
  for (int o = 1; o < 256; o <<= 1) {
    int v = 0; if (t >= o) v = sh[t - o];
    __syncthreads();
    sh[t] += v;
    __syncthreads();
  }
  loff[t] = (t == 0) ? 0 : sh[t - 1];
  if (t == 255) loff[256] = sh[255];
  __syncthreads();
  if (t < nn) off[n0 + t] = e0 + loff[t];
  // sinvp: coalesced, 8 per thread stride-256
  for (int i = t; i < 2048; i += 256) {
    int n = n0 + (i >> 3);
    if (n < N) {
      int c = cty[i];
      sinvp[(size_t)n * 8 + (i & 7)] = 1.0f / (float)(c > 1 ? c : 1);
    }
  }
  fill[t] = 0;
  __syncthreads();
  for (int e = e0 + t; e < e1; e += 256) {
    int v = tmp[e];
    int dl = (v >> 23) & 255;
    int pos = e0 + loff[dl] + atomicAdd(&fill[dl], 1);
    sps[pos] = v & 0x7FFFFF;
  }
}

// mark nodes whose h2 is read by layer 3: roots + src of root in-edges
__global__ void k_mark(const int* __restrict__ ridx, const int* __restrict__ off,
                       const int* __restrict__ sps, int* __restrict__ mark) {
  int i = blockIdx.x, t = threadIdx.x;
  int n = ridx[i];
  if (t == 0) mark[n] = 1;
  int e0 = off[n], e1 = off[n + 1];
  for (int e = e0 + t; e < e1; e += 64) mark[sps[e] & 0xFFFFF] = 1;
}

// all 4 weight tables upfront: q = blockIdx.y -> layer q/npass, pass q%npass
__global__ void k_tpw4(const float* __restrict__ wrel1, const float* __restrict__ root1,
                       const float* __restrict__ wrel2, const float* __restrict__ root2,
                       f16* __restrict__ Wt, int PW, int npass) {
  int row = blockIdx.x, k = threadIdx.x, q = blockIdx.y;
  int layer = q / npass, p = q - layer * npass;
  const float* wrel = layer ? wrel2 : wrel1;
  const float* wroot = layer ? root2 : root1;
  float v = 0.f;
  if (row < 9 * PW) {
    int cb = row / PW, j = row - cb * PW;
    int col = p * PW + j;
    v = (cb < 8) ? wrel[(size_t)cb * 16384 + k * 128 + col] : wroot[k * 128 + col];
  }
  Wt[(size_t)q * WTELEM + (size_t)row * 128 + k] = (f16)v;
}

// ---------------- GEMM: Y[9][M][PW] = blocked(A[M x 128] * Bt^T) ----------------
// grid (mb, 2): block handles col-tiles blockIdx.y, +gridDim.y, ...
// A (f16 or f32) staged once -> 16 reg fragments; As reused as repack buffer H.
// Swapped MFMA -> f16x4 LDS repack -> f16x8 stores into relation-blocked Y.
template <typename AT>
__global__ __launch_bounds__(256) void k_gemm3(const AT* __restrict__ A,
                                               const f16* __restrict__ Bt,
                                               f16* __restrict__ Y, int M, int ncol) {
  __shared__ f16 As[128 * 136];
  int tid = threadIdx.x;
  int m0 = blockIdx.x * 128;
  int PW = ncol / 9;
  int cbs = (PW == 64) ? 6 : 5;
#pragma unroll
  for (int cch = 0; cch < 8; cch++) {
    int ci = tid + cch * 256;
    int row = ci >> 4, c8 = ci & 15;
    int gm = m0 + row;
    f16x8 va = {};
    if (gm < M) {
      if constexpr (sizeof(AT) == 2) {
        va = *(const f16x8*)((const f16*)A + (size_t)gm * 128 + c8 * 8);
      } else {
        const float4* ap = (const float4*)((const float*)A + (size_t)gm * 128);
        float4 u0 = ap[c8 * 2], u1 = ap[c8 * 2 + 1];
        va[0] = (f16)u0.x; va[1] = (f16)u0.y; va[2] = (f16)u0.z; va[3] = (f16)u0.w;
        va[4] = (f16)u1.x; va[5] = (f16)u1.y; va[6] = (f16)u1.z; va[7] = (f16)u1.w;
      }
    }
    *(f16x8*)(As + row * 136 + c8 * 8) = va;
  }
  __syncthreads();
  int wid = tid >> 6, lane = tid & 63;
  int wm = (wid & 1) * 64, wn = (wid >> 1) * 64;
  int lm = lane & 15, lk = lane >> 4;
  f16x8 af[4][4];
#pragma unroll
  for (int ks = 0; ks < 4; ks++)
#pragma unroll
    for (int i = 0; i < 4; i++)
      af[ks][i] = *(const f16x8*)(As + (wm + i * 16 + lm) * 136 + ks * 32 + lk * 8);
  __syncthreads();
  f16* H = As;
  int NT = (ncol + 127) >> 7;
  for (int nt = blockIdx.y; nt < NT; nt += gridDim.y) {
    int n0 = nt * 128;
    f32x4 acc[4][4] = {};
#pragma unroll
    for (int ks = 0; ks < 4; ks++) {
      f16x8 b[4];
#pragma unroll
      for (int j = 0; j < 4; j++)
        b[j] = *(const f16x8*)(Bt + (size_t)(n0 + wn + j * 16 + lm) * 128 + ks * 32 + lk * 8);
#pragma unroll
      for (int i = 0; i < 4; i++)
#pragma unroll
        for (int j = 0; j < 4; j++)
          acc[i][j] = __builtin_amdgcn_mfma_f32_16x16x32_f16(b[j], af[ks][i], acc[i][j], 0, 0, 0);
    }
#pragma unroll
    for (int i = 0; i < 4; i++)
#pragma unroll
      for (int j = 0; j < 4; j++) {
        f16x4 o;
        o[0] = (f16)acc[i][j][0]; o[1] = (f16)acc[i][j][1];
        o[2] = (f16)acc[i][j][2]; o[3] = (f16)acc[i][j][3];
        *(f16x4*)(H + (wm + i * 16 + lm) * 136 + wn + j * 16 + lk * 4) = o;
      }
    __syncthreads();
    for (int i = tid; i < 128 * 16; i += 256) {
      int row = i >> 4, c8 = i & 15;
      int gm = m0 + row;
      int gc = n0 + c8 * 8;
      if (gm < M && gc < ncol) {
        int cb = gc >> cbs, wi = gc & (PW - 1);
        *(f16x8*)(Y + ((size_t)cb * M + gm) * PW + wi) =
            *(const f16x8*)(H + row * 136 + c8 * 8);
      }
    }
    __syncthreads();
  }
}

// ---------------- vectorized edge aggregation for one column pass ----------------
// Y is blocked [9][N][PW]; per edge reads contiguous f16x4 of Y[ty][src].
template <int PW>
__global__ __launch_bounds__(256) void k_edge_v(
    const f16* __restrict__ Y, const int* __restrict__ sps,
    const int* __restrict__ off, const float* __restrict__ sinvp,
    const float* __restrict__ bias, f16* __restrict__ hout,
    const int* __restrict__ mark, int N, int pass) {
  constexpr int CPL = PW / 16;
  int t = threadIdx.x;
  int g = t >> 4, st = t & 15;
  int n = blockIdx.x * 16 + g;
  if (n >= N) return;
  if (mark && !mark[n]) return;
  float sv = (st < 8) ? sinvp[n * 8 + st] : 0.f;
  int e0 = off[n], e1 = off[n + 1];
  float a[CPL], b2[CPL];
  {
    const f16* rp = Y + ((size_t)8 * N + n) * PW + st * CPL;
    const float* bp = bias + pass * PW + st * CPL;
#pragma unroll
    for (int q = 0; q < CPL; q++) { a[q] = (float)rp[q] + bp[q]; b2[q] = 0.f; }
  }
  int sgbase = t & 48;
  int e = e0;
  for (; e + 1 < e1; e += 2) {
    int p0 = sps[e], p1 = sps[e + 1];
    int s0 = p0 & 0xFFFFF, ty0 = ((unsigned)p0) >> 20;
    int s1 = p1 & 0xFFFFF, ty1 = ((unsigned)p1) >> 20;
    float sc0 = __shfl(sv, sgbase | ty0);
    float sc1 = __shfl(sv, sgbase | ty1);
    const f16* q0 = Y + ((size_t)ty0 * N + s0) * PW + st * CPL;
    const f16* q1 = Y + ((size_t)ty1 * N + s1) * PW + st * CPL;
    if constexpr (PW == 64) {
      f16x4 v0 = *(const f16x4*)q0;
      f16x4 v1 = *(const f16x4*)q1;
      a[0] += (float)v0[0] * sc0; a[1] += (float)v0[1] * sc0;
      a[2] += (float)v0[2] * sc0; a[3] += (float)v0[3] * sc0;
      b2[0] += (float)v1[0] * sc1; b2[1] += (float)v1[1] * sc1;
      b2[2] += (float)v1[2] * sc1; b2[3] += (float)v1[3] * sc1;
    } else {
      f16x2 v0 = *(const f16x2*)q0;
      f16x2 v1 = *(const f16x2*)q1;
      a[0] += (float)v0[0] * sc0; a[1] += (float)v0[1] * sc0;
      b2[0] += (float)v1[0] * sc1; b2[1] += (float)v1[1] * sc1;
    }
  }
  if (e < e1) {
    int p0 = sps[e];
    int s0 = p0 & 0xFFFFF, ty0 = ((unsigned)p0) >> 20;
    float sc0 = __shfl(sv, sgbase | ty0);
    const f16* q0 = Y + ((size_t)ty0 * N + s0) * PW + st * CPL;
    if constexpr (PW == 64) {
      f16x4 v0 = *(const f16x4*)q0;
      a[0] += (float)v0[0] * sc0; a[1] += (float)v0[1] * sc0;
      a[2] += (float)v0[2] * sc0; a[3] += (float)v0[3] * sc0;
    } else {
      f16x2 v0 = *(const f16x2*)q0;
      a[0] += (float)v0[0] * sc0; a[1] += (float)v0[1] * sc0;
    }
  }
  if constexpr (PW == 64) {
    f16x4 o;
#pragma unroll
    for (int q = 0; q < 4; q++) o[q] = (f16)fmaxf(a[q] + b2[q], 0.f);
    *(f16x4*)(hout + (size_t)n * 128 + pass * PW + st * 4) = o;
  } else {
    f16x2 o;
#pragma unroll
    for (int q = 0; q < 2; q++) o[q] = (f16)fmaxf(a[q] + b2[q], 0.f);
    *(f16x2*)(hout + (size_t)n * 128 + pass * PW + st * 2) = o;
  }
}

// ---------------- layer 3: only at root rows, weights in LDS ----------------
__global__ __launch_bounds__(128) void k_layer3(const f16* __restrict__ h2,
                                                const int* __restrict__ sps,
                                                const int* __restrict__ off,
                                                const float* __restrict__ sinvp,
                                                const int* __restrict__ ridx,
                                                const float* __restrict__ wrel,
                                                const float* __restrict__ wroot,
                                                const float* __restrict__ b3,
                                                float* __restrict__ out) {
  __shared__ f16 W[9 * 2048];
  __shared__ float red[2][16];
  __shared__ float sinv_s[8];
  int t = threadIdx.x;
  int n = ridx[blockIdx.x];
  for (int j = t; j < 9 * 2048; j += 128)
    W[j] = (f16)((j < 8 * 2048) ? wrel[j] : wroot[j - 8 * 2048]);
  if (t < 8) sinv_s[t] = sinvp[n * 8 + t];
  __syncthreads();
  int e0 = off[n], e1 = off[n + 1];
  int c = t & 15, kg = t >> 4;
  float a = 0.f;
  for (int e = e0; e < e1; e++) {
    int ps = sps[e];
    int s = ps & 0xFFFFF, ty = ((unsigned)ps) >> 20;
    float p = 0.f;
#pragma unroll
    for (int j = 0; j < 16; j++) {
      int k = kg * 16 + j;
      p += (float)h2[(size_t)s * 128 + k] * (float)W[ty * 2048 + k * 16 + c];
    }
    a += sinv_s[ty] * p;
  }
  {
    float p = 0.f;
#pragma unroll
    for (int j = 0; j < 16; j++) {
      int k = kg * 16 + j;
      p += (float)h2[(size_t)n * 128 + k] * (float)W[8 * 2048 + k * 16 + c];
    }
    a += p;
  }
  a += __shfl_xor(a, 16);
  a += __shfl_xor(a, 32);
  if ((t & 63) < 16) red[t >> 6][t & 15] = a;
  __syncthreads();
  if (t < 16) out[(size_t)blockIdx.x * 16 + t] = red[0][t] + red[1][t] + b3[t];
}

// ---------------- host ----------------
extern "C" void kernel_launch(void* const* d_in, const int* in_sizes, int n_in,
                              void* d_out, int out_size, void* d_ws, size_t ws_size,
                              hipStream_t stream) {
  const float* x     = (const float*)d_in[0];
  const int*   eidx  = (const int*)d_in[1];
  const int*   etyp  = (const int*)d_in[2];
  const int*   ridx  = (const int*)d_in[3];
  const float* wrel1 = (const float*)d_in[4];
  const float* root1 = (const float*)d_in[5];
  const float* b1    = (const float*)d_in[6];
  const float* wrel2 = (const float*)d_in[7];
  const float* root2 = (const float*)d_in[8];
  const float* b2    = (const float*)d_in[9];
  const float* wrel3 = (const float*)d_in[10];
  const float* root3 = (const float*)d_in[11];
  const float* b3    = (const float*)d_in[12];

  int N = in_sizes[0] / 128;
  int E = in_sizes[2];
  int NROOT = in_sizes[3];
  const int* esrc = eidx;
  const int* edst = eidx + E;

  char* p = (char*)d_ws;
  auto alloc = [&](size_t bytes) { void* r = (void*)p; p += (bytes + 255) & ~(size_t)255; return r; };
  int*   off   = (int*)alloc((size_t)(N + 1) * 4);
  int*   sps   = (int*)alloc((size_t)E * 4);
  f16*   h1    = (f16*)alloc((size_t)N * 128 * 2);
  f16*   h2    = (f16*)alloc((size_t)N * 128 * 2);   // written by L2-edge (marked rows)
  int*   mark  = (int*)alloc((size_t)N * 4);
  float* sinvp = (float*)alloc((size_t)N * 8 * 4);
  f16*   Wt    = (f16*)alloc((size_t)WTELEM * 2 * 8);   // up to 8 (layer,pass) tables
  int*   bcnt  = (int*)alloc(512 * 4);
  int*   boff  = (int*)alloc(513 * 4);
  int*   bfill = (int*)alloc(512 * 4);

  size_t used = (size_t)(p - (char*)d_ws);
  size_t remain = ws_size > used ? ws_size - used : 0;
  int PW = (remain >= (size_t)N * 9 * 64 * 2 + (1u << 20)) ? 64 : 32;
  int ldy = 9 * PW;
  f16* Y = (f16*)alloc((size_t)N * ldy * 2);
  // setup-only scratch lives in Y's region (dead until first GEMM writes Y):
  int* tmp  = (int*)Y;             // E ints (phase-A bucket-grouped edges)
  int* part = tmp + E;             // 4096 ints (fallback scan partials)
  int* fill = part + 4096;         // N ints (fallback scatter only)

  int nbuck = (N + 255) >> 8;
  int nbA = (E + ACHUNK - 1) / ACHUNK;
  int npass = 128 / PW;
  int NT = (ldy + 127) / 128;
  hipMemsetAsync(mark, 0, (size_t)N * 4, stream);
  k_tpw4<<<dim3(NT * 128, 2 * npass), 128, 0, stream>>>(wrel1, root1, wrel2, root2,
                                                        Wt, PW, npass);

  if (nbuck <= 512) {
    hipMemsetAsync(bcnt, 0, 512 * 4, stream);
    hipMemsetAsync(bfill, 0, 512 * 4, stream);
    k_bhist<<<nbA, 256, 0, stream>>>(edst, E, bcnt, nbuck);
    k_bscan<<<1, 512, 0, stream>>>(bcnt, boff, nbuck);
    k_bucketA<<<nbA, 256, 0, stream>>>(esrc, edst, etyp, E, boff, bfill, tmp, nbuck);
    k_bucketB3<<<nbuck, 256, 0, stream>>>(tmp, boff, off, sps, sinvp, N);
    k_sentinel<<<1, 1, 0, stream>>>(off + N, E);
  } else {
    int eb = (E + 255) / 256;
    hipMemsetAsync(off, 0, (size_t)(N + 1) * 4, stream);
    hipMemsetAsync(fill, 0, (size_t)N * 4, stream);
    k_hist<<<eb, 256, 0, stream>>>(edst, E, off);
    int nb1 = (N + 4095) / 4096;
    k_scan1<<<nb1, 256, 0, stream>>>(off, off, part, N);
    k_scan2<<<1, 256, 0, stream>>>(part, nb1);
    k_scan3<<<(N + 255) / 256, 256, 0, stream>>>(off, part, N);
    k_sentinel<<<1, 1, 0, stream>>>(off + N, E);
    k_scatter<<<eb, 256, 0, stream>>>(esrc, edst, etyp, E, off, fill, sps);
    int ng16f = (N + 15) / 16;
    k_sinvp<<<ng16f, 256, 0, stream>>>(sps, off, sinvp, N);
  }
  k_mark<<<NROOT, 64, 0, stream>>>(ridx, off, sps, mark);
  int ng16 = (N + 15) / 16;

  int mb = (N + 127) / 128;

  // layer 1: A = x (fp32, staged+converted in GEMM)
  for (int ps = 0; ps < npass; ps++) {
    k_gemm3<float><<<dim3(mb, 2), 256, 0, stream>>>(x, Wt + (size_t)ps * WTELEM, Y, N, ldy);
    if (PW == 64)
      k_edge_v<64><<<ng16, 256, 0, stream>>>(Y, sps, off, sinvp, b1, h1, nullptr, N, ps);
    else
      k_edge_v<32><<<ng16, 256, 0, stream>>>(Y, sps, off, sinvp, b1, h1, nullptr, N, ps);
  }
  // layer 2: A = h1, edge pass pruned to marked nodes
  for (int ps = 0; ps < npass; ps++) {
    k_gemm3<f16><<<dim3(mb, 2), 256, 0, stream>>>(h1, Wt + (size_t)(npass + ps) * WTELEM,
                                                  Y, N, ldy);
    if (PW == 64)
      k_edge_v<64><<<ng16, 256, 0, stream>>>(Y, sps, off, sinvp, b2, h2, mark, N, ps);
    else
      k_edge_v<32><<<ng16, 256, 0, stream>>>(Y, sps, off, sinvp, b2, h2, mark, N, ps);
  }
  k_layer3<<<NROOT, 128, 0, stream>>>(h2, sps, off, sinvp, ridx, wrel3, root3, b3,
                                      (float*)d_out);
}

// Round 15
// 446.231 us; speedup vs baseline: 1.1223x; 1.0668x over previous
//
#include <hip/hip_runtime.h>
#include <hip/hip_fp16.h>

// RGCN 3-layer. Layer 1: transform-first column-split (Y[9][N][PW] blocked,
// fp32-A GEMM, vectorized edge gather). Layer 2: AGGREGATE-FIRST on the
// ~17K marked nodes only: per-node per-relation mean of h1 -> compact
// Mc[nm x 1152] (8 means ++ h1[n]) -> one small GEMM vs Wcat[1152x128]
// -> h2c[nm x 128]. Layer 3 reads h2c via midx map (all accesses marked).
// Edge sort: bucket pipeline; bucketB3 emits off[] + sinvp in one pass.
// nm is device-side only (no host sync): kernels early-exit on *nm_p.

typedef _Float16 f16;
typedef _Float16 f16x2 __attribute__((ext_vector_type(2)));
typedef _Float16 f16x4 __attribute__((ext_vector_type(4)));
typedef _Float16 f16x8 __attribute__((ext_vector_type(8)));
typedef float f32x4 __attribute__((ext_vector_type(4)));

#define NREL 8
#define ACHUNK 8192
#define WTELEM (640 * 128)

// ---------------- fallback setup kernels (N > 131072 only) ----------------
__global__ void k_hist(const int* __restrict__ dst, int E, int* __restrict__ cnt) {
  int e = blockIdx.x * 256 + threadIdx.x;
  if (e < E) atomicAdd(&cnt[dst[e]], 1);
}

__global__ void k_scan1(const int* __restrict__ in, int* __restrict__ out,
                        int* __restrict__ part, int n) {
  __shared__ int sh[256];
  int b = blockIdx.x, t = threadIdx.x;
  int base = b * 4096 + t * 16;
  int v[16]; int s = 0;
#pragma unroll
  for (int j = 0; j < 16; j++) { int idx = base + j; int x = (idx < n) ? in[idx] : 0; v[j] = s; s += x; }
  sh[t] = s; __syncthreads();
  for (int off = 1; off < 256; off <<= 1) {
    int x = 0; if (t >= off) x = sh[t - off];
    __syncthreads();
    if (t >= off) sh[t] += x;
    __syncthreads();
  }
  int excl = (t == 0) ? 0 : sh[t - 1];
  if (t == 255) part[b] = sh[255];
#pragma unroll
  for (int j = 0; j < 16; j++) { int idx = base + j; if (idx < n) out[idx] = v[j] + excl; }
}

__global__ void k_scan2(int* __restrict__ part, int nb) {
  __shared__ int sh[256];
  int t = threadIdx.x;
  sh[t] = (t < nb) ? part[t] : 0; __syncthreads();
  for (int off = 1; off < 256; off <<= 1) {
    int x = 0; if (t >= off) x = sh[t - off];
    __syncthreads();
    if (t >= off) sh[t] += x;
    __syncthreads();
  }
  if (t < nb) part[t] = (t == 0) ? 0 : sh[t - 1];
}

__global__ void k_scan3(int* __restrict__ out, const int* __restrict__ part, int n) {
  int i = blockIdx.x * 256 + threadIdx.x;
  if (i < n) out[i] += part[i >> 12];
}

__global__ void k_scatter(const int* __restrict__ src, const int* __restrict__ dstv,
                          const int* __restrict__ et, int E,
                          const int* __restrict__ off, int* __restrict__ fill,
                          int* __restrict__ sps) {
  int e = blockIdx.x * 256 + threadIdx.x;
  if (e >= E) return;
  int d = dstv[e];
  int pos = off[d] + atomicAdd(&fill[d], 1);
  sps[pos] = src[e] | (et[e] << 20);
}

__global__ __launch_bounds__(256) void k_sinvp(const int* __restrict__ sps,
                                               const int* __restrict__ off,
                                               float* __restrict__ sinvp, int N) {
  __shared__ int c[16][8];
  int t = threadIdx.x;
  int g = t >> 4, st = t & 15;
  int n = blockIdx.x * 16 + g;
  if (st < 8) c[g][st] = 0;
  __syncthreads();
  if (n < N) {
    int e0 = off[n], e1 = off[n + 1];
    for (int e = e0 + st; e < e1; e += 16)
      atomicAdd(&c[g][((unsigned)sps[e]) >> 20], 1);
  }
  __syncthreads();
  if (n < N && st < 8) {
    int cc = c[g][st];
    sinvp[n * 8 + st] = 1.0f / (float)(cc > 1 ? cc : 1);
  }
}

__global__ void k_sentinel(int* __restrict__ p, int v) { *p = v; }

// ---------------- bucket pipeline (bucket = 256 consecutive dst nodes) ----------
__global__ __launch_bounds__(256) void k_bhist(const int* __restrict__ dstv, int E,
                                               int* __restrict__ bcnt, int nbuck) {
  __shared__ int h[512];
  int t = threadIdx.x;
  for (int i = t; i < 512; i += 256) h[i] = 0;
  __syncthreads();
  int lo = blockIdx.x * ACHUNK;
  int hi = lo + ACHUNK < E ? lo + ACHUNK : E;
  for (int e = lo + t; e < hi; e += 256) atomicAdd(&h[dstv[e] >> 8], 1);
  __syncthreads();
  for (int i = t; i < nbuck; i += 256)
    if (h[i]) atomicAdd(&bcnt[i], h[i]);
}

__global__ __launch_bounds__(512) void k_bscan(const int* __restrict__ bcnt,
                                               int* __restrict__ boff, int nbuck) {
  __shared__ int sh[512];
  int t = threadIdx.x;
  sh[t] = (t < nbuck) ? bcnt[t] : 0;
  __syncthreads();
  for (int o = 1; o < 512; o <<= 1) {
    int v = 0; if (t >= o) v = sh[t - o];
    __syncthreads();
    sh[t] += v;
    __syncthreads();
  }
  if (t <= nbuck && t < 512) boff[t] = (t == 0) ? 0 : sh[t - 1];
  if (t == 511 && nbuck >= 512) boff[nbuck] = sh[511];
}

__global__ __launch_bounds__(256) void k_bucketA(
    const int* __restrict__ src, const int* __restrict__ dstv,
    const int* __restrict__ et, int E, const int* __restrict__ boff,
    int* __restrict__ bfill, int* __restrict__ tmp, int nbuck) {
  __shared__ int hist[512];
  __shared__ int base[512];
  int t = threadIdx.x;
  int lo = blockIdx.x * ACHUNK;
  int hi = lo + ACHUNK < E ? lo + ACHUNK : E;
  for (int i = t; i < nbuck; i += 256) hist[i] = 0;
  __syncthreads();
  for (int e = lo + t; e < hi; e += 256)
    atomicAdd(&hist[dstv[e] >> 8], 1);
  __syncthreads();
  for (int i = t; i < nbuck; i += 256) {
    int c = hist[i];
    base[i] = c ? (boff[i] + atomicAdd(&bfill[i], c)) : 0;
  }
  __syncthreads();
  for (int e = lo + t; e < hi; e += 256) {
    int d = dstv[e];
    int b = d >> 8;
    int pos = atomicAdd(&base[b], 1);
    tmp[pos] = src[e] | (et[e] << 20) | ((d & 255) << 23);
  }
}

// Phase B: per-bucket (node,type) count -> off[] + sinvp[] + exact scatter
__global__ __launch_bounds__(256) void k_bucketB3(const int* __restrict__ tmp,
                                                  const int* __restrict__ boff,
                                                  int* __restrict__ off,
                                                  int* __restrict__ sps,
                                                  float* __restrict__ sinvp, int N) {
  __shared__ int cty[2048];
  __shared__ int sh[256];
  __shared__ int loff[257];
  __shared__ int fill[256];
  int b = blockIdx.x, t = threadIdx.x;
  int n0 = b << 8;
  int nn = (N - n0) < 256 ? (N - n0) : 256;
#pragma unroll
  for (int j = 0; j < 8; j++) cty[t + j * 256] = 0;
  __syncthreads();
  int e0 = boff[b], e1 = boff[b + 1];
  for (int e = e0 + t; e < e1; e += 256) {
    int v = tmp[e];
    int dl = (v >> 23) & 255, ty = (v >> 20) & 7;
    atomicAdd(&cty[dl * 8 + ty], 1);
  }
  __syncthreads();
  {
    int c = 0;
#pragma unroll
    for (int j = 0; j < 8; j++) c += cty[t * 8 + j];
    sh[t] = c;
  }
  __syncthreads();
  for (int o = 1; o < 256; o <<= 1) {
    int v = 0; if (t >= o) v = sh[t - o];
    __syncthreads();
    sh[t] += v;
    __syncthreads();
  }
  loff[t] = (t == 0) ? 0 : sh[t - 1];
  if (t == 255) loff[256] = sh[255];
  __syncthreads();
  if (t < nn) off[n0 + t] = e0 + loff[t];
  for (int i = t; i < 2048; i += 256) {
    int n = n0 + (i >> 3);
    if (n < N) {
      int c = cty[i];
      sinvp[(size_t)n * 8 + (i & 7)] = 1.0f / (float)(c > 1 ? c : 1);
    }
  }
  fill[t] = 0;
  __syncthreads();
  for (int e = e0 + t; e < e1; e += 256) {
    int v = tmp[e];
    int dl = (v >> 23) & 255;
    int pos = e0 + loff[dl] + atomicAdd(&fill[dl], 1);
    sps[pos] = v & 0x7FFFFF;
  }
}

// mark nodes whose h2 is read by layer 3: roots + src of root in-edges
__global__ void k_mark(const int* __restrict__ ridx, const int* __restrict__ off,
                       const int* __restrict__ sps, int* __restrict__ mark) {
  int i = blockIdx.x, t = threadIdx.x;
  int n = ridx[i];
  if (t == 0) mark[n] = 1;
  int e0 = off[n], e1 = off[n + 1];
  for (int e = e0 + t; e < e1; e += 64) mark[sps[e] & 0xFFFFF] = 1;
}

// compact marked nodes: mlist[i]=n, midx[n]=i, *nm = count
__global__ void k_compact(const int* __restrict__ mark, int* __restrict__ midx,
                          int* __restrict__ mlist, int* __restrict__ nm, int N) {
  int n = blockIdx.x * 256 + threadIdx.x;
  if (n < N && mark[n]) {
    int i = atomicAdd(nm, 1);
    midx[n] = i;
    mlist[i] = n;
  }
}

// layer-1 weight tables (one per pass): Wt[q][row][k]
__global__ void k_tpw4(const float* __restrict__ wrel1, const float* __restrict__ root1,
                       f16* __restrict__ Wt, int PW) {
  int row = blockIdx.x, k = threadIdx.x, q = blockIdx.y;
  float v = 0.f;
  if (row < 9 * PW) {
    int cb = row / PW, j = row - cb * PW;
    int col = q * PW + j;
    v = (cb < 8) ? wrel1[(size_t)cb * 16384 + k * 128 + col] : root1[k * 128 + col];
  }
  Wt[(size_t)q * WTELEM + (size_t)row * 128 + k] = (f16)v;
}

// layer-2 concat weights, transposed: Wc[c][r*128+k] = wrel2[r][k][c]; [c][1024+k] = root2[k][c]
__global__ void k_tpwc2(const float* __restrict__ wrel2, const float* __restrict__ root2,
                        f16* __restrict__ Wc) {
  int c = blockIdx.x, k = threadIdx.x;
#pragma unroll
  for (int r = 0; r < 8; r++)
    Wc[(size_t)c * 1152 + r * 128 + k] = (f16)wrel2[(size_t)r * 16384 + k * 128 + c];
  Wc[(size_t)c * 1152 + 1024 + k] = (f16)root2[(size_t)k * 128 + c];
}

// ---------------- layer-1 GEMM: Y[9][M][PW] = blocked(A[M x 128] * Bt^T) --------
template <typename AT>
__global__ __launch_bounds__(256) void k_gemm3(const AT* __restrict__ A,
                                               const f16* __restrict__ Bt,
                                               f16* __restrict__ Y, int M, int ncol) {
  __shared__ f16 As[128 * 136];
  int tid = threadIdx.x;
  int m0 = blockIdx.x * 128;
  int PW = ncol / 9;
  int cbs = (PW == 64) ? 6 : 5;
#pragma unroll
  for (int cch = 0; cch < 8; cch++) {
    int ci = tid + cch * 256;
    int row = ci >> 4, c8 = ci & 15;
    int gm = m0 + row;
    f16x8 va = {};
    if (gm < M) {
      if constexpr (sizeof(AT) == 2) {
        va = *(const f16x8*)((const f16*)A + (size_t)gm * 128 + c8 * 8);
      } else {
        const float4* ap = (const float4*)((const float*)A + (size_t)gm * 128);
        float4 u0 = ap[c8 * 2], u1 = ap[c8 * 2 + 1];
        va[0] = (f16)u0.x; va[1] = (f16)u0.y; va[2] = (f16)u0.z; va[3] = (f16)u0.w;
        va[4] = (f16)u1.x; va[5] = (f16)u1.y; va[6] = (f16)u1.z; va[7] = (f16)u1.w;
      }
    }
    *(f16x8*)(As + row * 136 + c8 * 8) = va;
  }
  __syncthreads();
  int wid = tid >> 6, lane = tid & 63;
  int wm = (wid & 1) * 64, wn = (wid >> 1) * 64;
  int lm = lane & 15, lk = lane >> 4;
  f16x8 af[4][4];
#pragma unroll
  for (int ks = 0; ks < 4; ks++)
#pragma unroll
    for (int i = 0; i < 4; i++)
      af[ks][i] = *(const f16x8*)(As + (wm + i * 16 + lm) * 136 + ks * 32 + lk * 8);
  __syncthreads();
  f16* H = As;
  int NT = (ncol + 127) >> 7;
  for (int nt = blockIdx.y; nt < NT; nt += gridDim.y) {
    int n0 = nt * 128;
    f32x4 acc[4][4] = {};
#pragma unroll
    for (int ks = 0; ks < 4; ks++) {
      f16x8 b[4];
#pragma unroll
      for (int j = 0; j < 4; j++)
        b[j] = *(const f16x8*)(Bt + (size_t)(n0 + wn + j * 16 + lm) * 128 + ks * 32 + lk * 8);
#pragma unroll
      for (int i = 0; i < 4; i++)
#pragma unroll
        for (int j = 0; j < 4; j++)
          acc[i][j] = __builtin_amdgcn_mfma_f32_16x16x32_f16(b[j], af[ks][i], acc[i][j], 0, 0, 0);
    }
#pragma unroll
    for (int i = 0; i < 4; i++)
#pragma unroll
      for (int j = 0; j < 4; j++) {
        f16x4 o;
        o[0] = (f16)acc[i][j][0]; o[1] = (f16)acc[i][j][1];
        o[2] = (f16)acc[i][j][2]; o[3] = (f16)acc[i][j][3];
        *(f16x4*)(H + (wm + i * 16 + lm) * 136 + wn + j * 16 + lk * 4) = o;
      }
    __syncthreads();
    for (int i = tid; i < 128 * 16; i += 256) {
      int row = i >> 4, c8 = i & 15;
      int gm = m0 + row;
      int gc = n0 + c8 * 8;
      if (gm < M && gc < ncol) {
        int cb = gc >> cbs, wi = gc & (PW - 1);
        *(f16x8*)(Y + ((size_t)cb * M + gm) * PW + wi) =
            *(const f16x8*)(H + row * 136 + c8 * 8);
      }
    }
    __syncthreads();
  }
}

// ---------------- layer-1 edge aggregation (Y blocked [9][N][PW]) ----------------
template <int PW>
__global__ __launch_bounds__(256) void k_edge_v(
    const f16* __restrict__ Y, const int* __restrict__ sps,
    const int* __restrict__ off, const float* __restrict__ sinvp,
    const float* __restrict__ bias, f16* __restrict__ hout, int N, int pass) {
  constexpr int CPL = PW / 16;
  int t = threadIdx.x;
  int g = t >> 4, st = t & 15;
  int n = blockIdx.x * 16 + g;
  if (n >= N) return;
  float sv = (st < 8) ? sinvp[n * 8 + st] : 0.f;
  int e0 = off[n], e1 = off[n + 1];
  float a[CPL], b2[CPL];
  {
    const f16* rp = Y + ((size_t)8 * N + n) * PW + st * CPL;
    const float* bp = bias + pass * PW + st * CPL;
#pragma unroll
    for (int q = 0; q < CPL; q++) { a[q] = (float)rp[q] + bp[q]; b2[q] = 0.f; }
  }
  int sgbase = t & 48;
  int e = e0;
  for (; e + 1 < e1; e += 2) {
    int p0 = sps[e], p1 = sps[e + 1];
    int s0 = p0 & 0xFFFFF, ty0 = ((unsigned)p0) >> 20;
    int s1 = p1 & 0xFFFFF, ty1 = ((unsigned)p1) >> 20;
    float sc0 = __shfl(sv, sgbase | ty0);
    float sc1 = __shfl(sv, sgbase | ty1);
    const f16* q0 = Y + ((size_t)ty0 * N + s0) * PW + st * CPL;
    const f16* q1 = Y + ((size_t)ty1 * N + s1) * PW + st * CPL;
    if constexpr (PW == 64) {
      f16x4 v0 = *(const f16x4*)q0;
      f16x4 v1 = *(const f16x4*)q1;
      a[0] += (float)v0[0] * sc0; a[1] += (float)v0[1] * sc0;
      a[2] += (float)v0[2] * sc0; a[3] += (float)v0[3] * sc0;
      b2[0] += (float)v1[0] * sc1; b2[1] += (float)v1[1] * sc1;
      b2[2] += (float)v1[2] * sc1; b2[3] += (float)v1[3] * sc1;
    } else {
      f16x2 v0 = *(const f16x2*)q0;
      f16x2 v1 = *(const f16x2*)q1;
      a[0] += (float)v0[0] * sc0; a[1] += (float)v0[1] * sc0;
      b2[0] += (float)v1[0] * sc1; b2[1] += (float)v1[1] * sc1;
    }
  }
  if (e < e1) {
    int p0 = sps[e];
    int s0 = p0 & 0xFFFFF, ty0 = ((unsigned)p0) >> 20;
    float sc0 = __shfl(sv, sgbase | ty0);
    const f16* q0 = Y + ((size_t)ty0 * N + s0) * PW + st * CPL;
    if constexpr (PW == 64) {
      f16x4 v0 = *(const f16x4*)q0;
      a[0] += (float)v0[0] * sc0; a[1] += (float)v0[1] * sc0;
      a[2] += (float)v0[2] * sc0; a[3] += (float)v0[3] * sc0;
    } else {
      f16x2 v0 = *(const f16x2*)q0;
      a[0] += (float)v0[0] * sc0; a[1] += (float)v0[1] * sc0;
    }
  }
  if constexpr (PW == 64) {
    f16x4 o;
#pragma unroll
    for (int q = 0; q < 4; q++) o[q] = (f16)fmaxf(a[q] + b2[q], 0.f);
    *(f16x4*)(hout + (size_t)n * 128 + pass * PW + st * 4) = o;
  } else {
    f16x2 o;
#pragma unroll
    for (int q = 0; q < 2; q++) o[q] = (f16)fmaxf(a[q] + b2[q], 0.f);
    *(f16x2*)(hout + (size_t)n * 128 + pass * PW + st * 2) = o;
  }
}

// ---------------- layer-2 aggregate-first: per-marked-node relation means --------
__global__ __launch_bounds__(128) void k_agg2(
    const f16* __restrict__ h1, const int* __restrict__ sps,
    const int* __restrict__ off, const float* __restrict__ sinvp,
    const int* __restrict__ mlist, const int* __restrict__ nm_p,
    f16* __restrict__ Mc, int cap) {
  int nm = *nm_p; if (nm > cap) nm = cap;
  int t = threadIdx.x;
  for (int i = blockIdx.x; i < nm; i += gridDim.x) {
    int n = mlist[i];
    int e0 = off[n], e1 = off[n + 1];
    float acc[8];
#pragma unroll
    for (int r = 0; r < 8; r++) acc[r] = 0.f;
    int e = e0;
    for (; e + 1 < e1; e += 2) {
      int p0 = sps[e], p1 = sps[e + 1];
      int s0 = p0 & 0xFFFFF, ty0 = ((unsigned)p0) >> 20;
      int s1 = p1 & 0xFFFFF, ty1 = ((unsigned)p1) >> 20;
      float v0 = (float)h1[(size_t)s0 * 128 + t];
      float v1 = (float)h1[(size_t)s1 * 128 + t];
#pragma unroll
      for (int r = 0; r < 8; r++) {
        acc[r] += (ty0 == r) ? v0 : 0.f;
        acc[r] += (ty1 == r) ? v1 : 0.f;
      }
    }
    if (e < e1) {
      int p0 = sps[e];
      int s0 = p0 & 0xFFFFF, ty0 = ((unsigned)p0) >> 20;
      float v0 = (float)h1[(size_t)s0 * 128 + t];
#pragma unroll
      for (int r = 0; r < 8; r++) acc[r] += (ty0 == r) ? v0 : 0.f;
    }
    f16* mp = Mc + (size_t)i * 1152;
#pragma unroll
    for (int r = 0; r < 8; r++)
      mp[r * 128 + t] = (f16)(acc[r] * sinvp[(size_t)n * 8 + r]);
    mp[1024 + t] = h1[(size_t)n * 128 + t];
  }
}

// ---------------- compact layer-2 GEMM: h2c = relu(Mc[nm x 1152] @ Wc^T + b2) ----
__global__ __launch_bounds__(256) void k_gemm_c(const f16* __restrict__ Mc,
                                                const f16* __restrict__ Wc,
                                                const float* __restrict__ bias,
                                                const int* __restrict__ nm_p,
                                                f16* __restrict__ h2c, int cap) {
  int nm = *nm_p; if (nm > cap) nm = cap;
  int m0 = blockIdx.x * 128;
  if (m0 >= nm) return;
  __shared__ f16 As[128 * 136];
  int tid = threadIdx.x;
  int wid = tid >> 6, lane = tid & 63;
  int wm = (wid & 1) * 64, wn = (wid >> 1) * 64;
  int lm = lane & 15, lk = lane >> 4;
  f32x4 acc[4][4] = {};
  for (int kc = 0; kc < 9; kc++) {
    __syncthreads();
#pragma unroll
    for (int cch = 0; cch < 8; cch++) {
      int ci = tid + cch * 256;
      int row = ci >> 4, c8 = ci & 15;
      int gm = m0 + row;
      f16x8 va = {};
      if (gm < nm) va = *(const f16x8*)(Mc + (size_t)gm * 1152 + kc * 128 + c8 * 8);
      *(f16x8*)(As + row * 136 + c8 * 8) = va;
    }
    __syncthreads();
#pragma unroll
    for (int ks = 0; ks < 4; ks++) {
      f16x8 a[4], b[4];
#pragma unroll
      for (int j = 0; j < 4; j++)
        b[j] = *(const f16x8*)(Wc + (size_t)(wn + j * 16 + lm) * 1152 + kc * 128 + ks * 32 + lk * 8);
#pragma unroll
      for (int i = 0; i < 4; i++)
        a[i] = *(const f16x8*)(As + (wm + i * 16 + lm) * 136 + ks * 32 + lk * 8);
#pragma unroll
      for (int i = 0; i < 4; i++)
#pragma unroll
        for (int j = 0; j < 4; j++)
          acc[i][j] = __builtin_amdgcn_mfma_f32_16x16x32_f16(b[j], a[i], acc[i][j], 0, 0, 0);
    }
  }
  __syncthreads();
  f16* H = As;
#pragma unroll
  for (int i = 0; i < 4; i++)
#pragma unroll
    for (int j = 0; j < 4; j++) {
      f16x4 o;
#pragma unroll
      for (int q = 0; q < 4; q++)
        o[q] = (f16)fmaxf(acc[i][j][q] + bias[wn + j * 16 + lk * 4 + q], 0.f);
      *(f16x4*)(H + (wm + i * 16 + lm) * 136 + wn + j * 16 + lk * 4) = o;
    }
  __syncthreads();
  for (int i = tid; i < 128 * 16; i += 256) {
    int row = i >> 4, c8 = i & 15;
    int gm = m0 + row;
    if (gm < nm)
      *(f16x8*)(h2c + (size_t)gm * 128 + c8 * 8) = *(const f16x8*)(H + row * 136 + c8 * 8);
  }
}

// ---------------- layer 3: root rows only, h2c via midx, weights in LDS ----------
__global__ __launch_bounds__(128) void k_layer3c(const f16* __restrict__ h2c,
                                                 const int* __restrict__ midx,
                                                 const int* __restrict__ sps,
                                                 const int* __restrict__ off,
                                                 const float* __restrict__ sinvp,
                                                 const int* __restrict__ ridx,
                                                 const float* __restrict__ wrel,
                                                 const float* __restrict__ wroot,
                                                 const float* __restrict__ b3,
                                                 float* __restrict__ out) {
  __shared__ f16 W[9 * 2048];
  __shared__ float red[2][16];
  __shared__ float sinv_s[8];
  int t = threadIdx.x;
  int n = ridx[blockIdx.x];
  for (int j = t; j < 9 * 2048; j += 128)
    W[j] = (f16)((j < 8 * 2048) ? wrel[j] : wroot[j - 8 * 2048]);
  if (t < 8) sinv_s[t] = sinvp[n * 8 + t];
  __syncthreads();
  int e0 = off[n], e1 = off[n + 1];
  int c = t & 15, kg = t >> 4;
  float a = 0.f;
  for (int e = e0; e < e1; e++) {
    int ps = sps[e];
    int s = ps & 0xFFFFF, ty = ((unsigned)ps) >> 20;
    int si = midx[s];
    float p = 0.f;
#pragma unroll
    for (int j = 0; j < 16; j++) {
      int k = kg * 16 + j;
      p += (float)h2c[(size_t)si * 128 + k] * (float)W[ty * 2048 + k * 16 + c];
    }
    a += sinv_s[ty] * p;
  }
  {
    int ni = midx[n];
    float p = 0.f;
#pragma unroll
    for (int j = 0; j < 16; j++) {
      int k = kg * 16 + j;
      p += (float)h2c[(size_t)ni * 128 + k] * (float)W[8 * 2048 + k * 16 + c];
    }
    a += p;
  }
  a += __shfl_xor(a, 16);
  a += __shfl_xor(a, 32);
  if ((t & 63) < 16) red[t >> 6][t & 15] = a;
  __syncthreads();
  if (t < 16) out[(size_t)blockIdx.x * 16 + t] = red[0][t] + red[1][t] + b3[t];
}

// ---------------- host ----------------
extern "C" void kernel_launch(void* const* d_in, const int* in_sizes, int n_in,
                              void* d_out, int out_size, void* d_ws, size_t ws_size,
                              hipStream_t stream) {
  const float* x     = (const float*)d_in[0];
  const int*   eidx  = (const int*)d_in[1];
  const int*   etyp  = (const int*)d_in[2];
  const int*   ridx  = (const int*)d_in[3];
  const float* wrel1 = (const float*)d_in[4];
  const float* root1 = (const float*)d_in[5];
  const float* b1    = (const float*)d_in[6];
  const float* wrel2 = (const float*)d_in[7];
  const float* root2 = (const float*)d_in[8];
  const float* b2    = (const float*)d_in[9];
  const float* wrel3 = (const float*)d_in[10];
  const float* root3 = (const float*)d_in[11];
  const float* b3    = (const float*)d_in[12];

  int N = in_sizes[0] / 128;
  int E = in_sizes[2];
  int NROOT = in_sizes[3];
  const int* esrc = eidx;
  const int* edst = eidx + E;

  char* p = (char*)d_ws;
  auto alloc = [&](size_t bytes) { void* r = (void*)p; p += (bytes + 255) & ~(size_t)255; return r; };
  int*   off   = (int*)alloc((size_t)(N + 1) * 4);
  int*   sps   = (int*)alloc((size_t)E * 4);
  f16*   h1    = (f16*)alloc((size_t)N * 128 * 2);
  f16*   h2c   = (f16*)alloc((size_t)N * 128 * 2);   // compact layer-2 output
  int*   mark  = (int*)alloc((size_t)N * 4);
  int*   midx  = (int*)alloc((size_t)N * 4);
  int*   mlist = (int*)alloc((size_t)N * 4);
  int*   nmv   = (int*)alloc(256);
  float* sinvp = (float*)alloc((size_t)N * 8 * 4);
  f16*   Wt    = (f16*)alloc((size_t)WTELEM * 2 * 4);   // layer-1 pass tables
  f16*   Wc    = (f16*)alloc((size_t)128 * 1152 * 2);   // layer-2 concat (transposed)
  int*   bcnt  = (int*)alloc(512 * 4);
  int*   boff  = (int*)alloc(513 * 4);
  int*   bfill = (int*)alloc(512 * 4);

  size_t used = (size_t)(p - (char*)d_ws);
  size_t remain = ws_size > used ? ws_size - used : 0;
  int PW = (remain >= (size_t)N * 9 * 64 * 2 + (1u << 20)) ? 64 : 32;
  int ldy = 9 * PW;
  f16* Y = (f16*)alloc((size_t)N * ldy * 2);
  // setup scratch aliases Y (dead until first GEMM); Mc aliases Y (layer-2 phase)
  int* tmp  = (int*)Y;
  int* part = tmp + E;
  int* fill = part + 4096;
  f16* Mc   = Y;
  int  cap  = (int)(((size_t)N * ldy) / 1152);   // Mc rows that fit in Y region

  int nbuck = (N + 255) >> 8;
  int nbA = (E + ACHUNK - 1) / ACHUNK;
  int npass = 128 / PW;
  int NT = (ldy + 127) / 128;
  hipMemsetAsync(mark, 0, (size_t)N * 4, stream);
  hipMemsetAsync(nmv, 0, 256, stream);
  k_tpw4<<<dim3(NT * 128, npass), 128, 0, stream>>>(wrel1, root1, Wt, PW);
  k_tpwc2<<<128, 128, 0, stream>>>(wrel2, root2, Wc);

  if (nbuck <= 512) {
    hipMemsetAsync(bcnt, 0, 512 * 4, stream);
    hipMemsetAsync(bfill, 0, 512 * 4, stream);
    k_bhist<<<nbA, 256, 0, stream>>>(edst, E, bcnt, nbuck);
    k_bscan<<<1, 512, 0, stream>>>(bcnt, boff, nbuck);
    k_bucketA<<<nbA, 256, 0, stream>>>(esrc, edst, etyp, E, boff, bfill, tmp, nbuck);
    k_bucketB3<<<nbuck, 256, 0, stream>>>(tmp, boff, off, sps, sinvp, N);
    k_sentinel<<<1, 1, 0, stream>>>(off + N, E);
  } else {
    int eb = (E + 255) / 256;
    hipMemsetAsync(off, 0, (size_t)(N + 1) * 4, stream);
    hipMemsetAsync(fill, 0, (size_t)N * 4, stream);
    k_hist<<<eb, 256, 0, stream>>>(edst, E, off);
    int nb1 = (N + 4095) / 4096;
    k_scan1<<<nb1, 256, 0, stream>>>(off, off, part, N);
    k_scan2<<<1, 256, 0, stream>>>(part, nb1);
    k_scan3<<<(N + 255) / 256, 256, 0, stream>>>(off, part, N);
    k_sentinel<<<1, 1, 0, stream>>>(off + N, E);
    k_scatter<<<eb, 256, 0, stream>>>(esrc, edst, etyp, E, off, fill, sps);
    int ng16f = (N + 15) / 16;
    k_sinvp<<<ng16f, 256, 0, stream>>>(sps, off, sinvp, N);
  }
  k_mark<<<NROOT, 64, 0, stream>>>(ridx, off, sps, mark);
  k_compact<<<(N + 255) / 256, 256, 0, stream>>>(mark, midx, mlist, nmv, N);
  int ng16 = (N + 15) / 16;

  int mb = (N + 127) / 128;

  // layer 1: transform-first, A = x (fp32, staged+converted in GEMM)
  for (int ps = 0; ps < npass; ps++) {
    k_gemm3<float><<<dim3(mb, 2), 256, 0, stream>>>(x, Wt + (size_t)ps * WTELEM, Y, N, ldy);
    if (PW == 64)
      k_edge_v<64><<<ng16, 256, 0, stream>>>(Y, sps, off, sinvp, b1, h1, N, ps);
    else
      k_edge_v<32><<<ng16, 256, 0, stream>>>(Y, sps, off, sinvp, b1, h1, N, ps);
  }
  // layer 2: aggregate-first on marked nodes (Y region reused as Mc)
  k_agg2<<<2048, 128, 0, stream>>>(h1, sps, off, sinvp, mlist, nmv, Mc, cap);
  k_gemm_c<<<(cap + 127) / 128, 256, 0, stream>>>(Mc, Wc, b2, nmv, h2c, cap);
  // layer 3: roots only, compact h2
  k_layer3c<<<NROOT, 128, 0, stream>>>(h2c, midx, sps, off, sinvp, ridx, wrel3, root3,
                                       b3, (float*)d_out);
}

// Round 16
// 431.294 us; speedup vs baseline: 1.1612x; 1.0346x over previous
//
#include <hip/hip_runtime.h>
#include <hip/hip_fp16.h>

// RGCN 3-layer. Layer 1: transform-first column-split (Y[9][N][PW] blocked,
// f16-A GEMM with x pre-converted into the dead h2c buffer, vectorized edge
// gather w/ 4-deep unroll). Layer 2: aggregate-first on ~17K marked nodes ->
// compact Mc[nm x 1152] -> one small GEMM -> h2c. Layer 3 reads h2c via midx.
// Edge sort: bucket pipeline; bucketB3 emits off[] + sinvp in one pass.
// nm is device-side only (no host sync): kernels early-exit on *nm_p.

typedef _Float16 f16;
typedef _Float16 f16x2 __attribute__((ext_vector_type(2)));
typedef _Float16 f16x4 __attribute__((ext_vector_type(4)));
typedef _Float16 f16x8 __attribute__((ext_vector_type(8)));
typedef float f32x4 __attribute__((ext_vector_type(4)));

#define NREL 8
#define ACHUNK 8192
#define WTELEM (640 * 128)

// ---------------- fallback setup kernels (N > 131072 only) ----------------
__global__ void k_hist(const int* __restrict__ dst, int E, int* __restrict__ cnt) {
  int e = blockIdx.x * 256 + threadIdx.x;
  if (e < E) atomicAdd(&cnt[dst[e]], 1);
}

__global__ void k_scan1(const int* __restrict__ in, int* __restrict__ out,
                        int* __restrict__ part, int n) {
  __shared__ int sh[256];
  int b = blockIdx.x, t = threadIdx.x;
  int base = b * 4096 + t * 16;
  int v[16]; int s = 0;
#pragma unroll
  for (int j = 0; j < 16; j++) { int idx = base + j; int x = (idx < n) ? in[idx] : 0; v[j] = s; s += x; }
  sh[t] = s; __syncthreads();
  for (int off = 1; off < 256; off <<= 1) {
    int x = 0; if (t >= off) x = sh[t - off];
    __syncthreads();
    if (t >= off) sh[t] += x;
    __syncthreads();
  }
  int excl = (t == 0) ? 0 : sh[t - 1];
  if (t == 255) part[b] = sh[255];
#pragma unroll
  for (int j = 0; j < 16; j++) { int idx = base + j; if (idx < n) out[idx] = v[j] + excl; }
}

__global__ void k_scan2(int* __restrict__ part, int nb) {
  __shared__ int sh[256];
  int t = threadIdx.x;
  sh[t] = (t < nb) ? part[t] : 0; __syncthreads();
  for (int off = 1; off < 256; off <<= 1) {
    int x = 0; if (t >= off) x = sh[t - off];
    __syncthreads();
    if (t >= off) sh[t] += x;
    __syncthreads();
  }
  if (t < nb) part[t] = (t == 0) ? 0 : sh[t - 1];
}

__global__ void k_scan3(int* __restrict__ out, const int* __restrict__ part, int n) {
  int i = blockIdx.x * 256 + threadIdx.x;
  if (i < n) out[i] += part[i >> 12];
}

__global__ void k_scatter(const int* __restrict__ src, const int* __restrict__ dstv,
                          const int* __restrict__ et, int E,
                          const int* __restrict__ off, int* __restrict__ fill,
                          int* __restrict__ sps) {
  int e = blockIdx.x * 256 + threadIdx.x;
  if (e >= E) return;
  int d = dstv[e];
  int pos = off[d] + atomicAdd(&fill[d], 1);
  sps[pos] = src[e] | (et[e] << 20);
}

__global__ __launch_bounds__(256) void k_sinvp(const int* __restrict__ sps,
                                               const int* __restrict__ off,
                                               float* __restrict__ sinvp, int N) {
  __shared__ int c[16][8];
  int t = threadIdx.x;
  int g = t >> 4, st = t & 15;
  int n = blockIdx.x * 16 + g;
  if (st < 8) c[g][st] = 0;
  __syncthreads();
  if (n < N) {
    int e0 = off[n], e1 = off[n + 1];
    for (int e = e0 + st; e < e1; e += 16)
      atomicAdd(&c[g][((unsigned)sps[e]) >> 20], 1);
  }
  __syncthreads();
  if (n < N && st < 8) {
    int cc = c[g][st];
    sinvp[n * 8 + st] = 1.0f / (float)(cc > 1 ? cc : 1);
  }
}

__global__ void k_sentinel(int* __restrict__ p, int v) { *p = v; }

// zero bcnt/bfill/nmv/mark in one launch
__global__ void k_init(int* __restrict__ bcnt, int* __restrict__ bfill,
                       int* __restrict__ nmv, int* __restrict__ mark, int N) {
  int i = blockIdx.x * 256 + threadIdx.x;
  if (i < 512) { bcnt[i] = 0; bfill[i] = 0; }
  if (i < 64) nmv[i] = 0;
  if (i < N) mark[i] = 0;
}

// ---------------- bucket pipeline (bucket = 256 consecutive dst nodes) ----------
__global__ __launch_bounds__(256) void k_bhist(const int* __restrict__ dstv, int E,
                                               int* __restrict__ bcnt, int nbuck) {
  __shared__ int h[512];
  int t = threadIdx.x;
  for (int i = t; i < 512; i += 256) h[i] = 0;
  __syncthreads();
  int lo = blockIdx.x * ACHUNK;
  int hi = lo + ACHUNK < E ? lo + ACHUNK : E;
  for (int e = lo + t; e < hi; e += 256) atomicAdd(&h[dstv[e] >> 8], 1);
  __syncthreads();
  for (int i = t; i < nbuck; i += 256)
    if (h[i]) atomicAdd(&bcnt[i], h[i]);
}

__global__ __launch_bounds__(512) void k_bscan(const int* __restrict__ bcnt,
                                               int* __restrict__ boff, int nbuck) {
  __shared__ int sh[512];
  int t = threadIdx.x;
  sh[t] = (t < nbuck) ? bcnt[t] : 0;
  __syncthreads();
  for (int o = 1; o < 512; o <<= 1) {
    int v = 0; if (t >= o) v = sh[t - o];
    __syncthreads();
    sh[t] += v;
    __syncthreads();
  }
  if (t <= nbuck && t < 512) boff[t] = (t == 0) ? 0 : sh[t - 1];
  if (t == 511 && nbuck >= 512) boff[nbuck] = sh[511];
}

__global__ __launch_bounds__(256) void k_bucketA(
    const int* __restrict__ src, const int* __restrict__ dstv,
    const int* __restrict__ et, int E, const int* __restrict__ boff,
    int* __restrict__ bfill, int* __restrict__ tmp, int nbuck) {
  __shared__ int hist[512];
  __shared__ int base[512];
  int t = threadIdx.x;
  int lo = blockIdx.x * ACHUNK;
  int hi = lo + ACHUNK < E ? lo + ACHUNK : E;
  for (int i = t; i < nbuck; i += 256) hist[i] = 0;
  __syncthreads();
  for (int e = lo + t; e < hi; e += 256)
    atomicAdd(&hist[dstv[e] >> 8], 1);
  __syncthreads();
  for (int i = t; i < nbuck; i += 256) {
    int c = hist[i];
    base[i] = c ? (boff[i] + atomicAdd(&bfill[i], c)) : 0;
  }
  __syncthreads();
  for (int e = lo + t; e < hi; e += 256) {
    int d = dstv[e];
    int b = d >> 8;
    int pos = atomicAdd(&base[b], 1);
    tmp[pos] = src[e] | (et[e] << 20) | ((d & 255) << 23);
  }
}

// Phase B: per-bucket (node,type) count -> off[] + sinvp[] + exact scatter
__global__ __launch_bounds__(256) void k_bucketB3(const int* __restrict__ tmp,
                                                  const int* __restrict__ boff,
                                                  int* __restrict__ off,
                                                  int* __restrict__ sps,
                                                  float* __restrict__ sinvp, int N) {
  __shared__ int cty[2048];
  __shared__ int sh[256];
  __shared__ int loff[257];
  __shared__ int fill[256];
  int b = blockIdx.x, t = threadIdx.x;
  int n0 = b << 8;
  int nn = (N - n0) < 256 ? (N - n0) : 256;
#pragma unroll
  for (int j = 0; j < 8; j++) cty[t + j * 256] = 0;
  __syncthreads();
  int e0 = boff[b], e1 = boff[b + 1];
  for (int e = e0 + t; e < e1; e += 256) {
    int v = tmp[e];
    int dl = (v >> 23) & 255, ty = (v >> 20) & 7;
    atomicAdd(&cty[dl * 8 + ty], 1);
  }
  __syncthreads();
  {
    int c = 0;
#pragma unroll
    for (int j = 0; j < 8; j++) c += cty[t * 8 + j];
    sh[t] = c;
  }
  __syncthreads();
  for (int o = 1; o < 256; o <<= 1) {
    int v = 0; if (t >= o) v = sh[t - o];
    __syncthreads();
    sh[t] += v;
    __syncthreads();
  }
  loff[t] = (t == 0) ? 0 : sh[t - 1];
  if (t == 255) loff[256] = sh[255];
  __syncthreads();
  if (t < nn) off[n0 + t] = e0 + loff[t];
  for (int i = t; i < 2048; i += 256) {
    int n = n0 + (i >> 3);
    if (n < N) {
      int c = cty[i];
      sinvp[(size_t)n * 8 + (i & 7)] = 1.0f / (float)(c > 1 ? c : 1);
    }
  }
  fill[t] = 0;
  __syncthreads();
  for (int e = e0 + t; e < e1; e += 256) {
    int v = tmp[e];
    int dl = (v >> 23) & 255;
    int pos = e0 + loff[dl] + atomicAdd(&fill[dl], 1);
    sps[pos] = v & 0x7FFFFF;
  }
}

// mark nodes whose h2 is read by layer 3: roots + src of root in-edges
__global__ void k_mark(const int* __restrict__ ridx, const int* __restrict__ off,
                       const int* __restrict__ sps, int* __restrict__ mark) {
  int i = blockIdx.x, t = threadIdx.x;
  int n = ridx[i];
  if (t == 0) mark[n] = 1;
  int e0 = off[n], e1 = off[n + 1];
  for (int e = e0 + t; e < e1; e += 64) mark[sps[e] & 0xFFFFF] = 1;
}

// compact marked nodes: mlist[i]=n, midx[n]=i, *nm = count
__global__ void k_compact(const int* __restrict__ mark, int* __restrict__ midx,
                          int* __restrict__ mlist, int* __restrict__ nm, int N) {
  int n = blockIdx.x * 256 + threadIdx.x;
  if (n < N && mark[n]) {
    int i = atomicAdd(nm, 1);
    midx[n] = i;
    mlist[i] = n;
  }
}

__global__ void k_f32_to_f16(const float* __restrict__ in, f16* __restrict__ out, int n4) {
  int i = blockIdx.x * 256 + threadIdx.x;
  if (i < n4) {
    float4 v = ((const float4*)in)[i];
    f16x4 o; o[0] = (f16)v.x; o[1] = (f16)v.y; o[2] = (f16)v.z; o[3] = (f16)v.w;
    ((f16x4*)out)[i] = o;
  }
}

// layer-1 weight tables (one per pass): Wt[q][row][k]
__global__ void k_tpw4(const float* __restrict__ wrel1, const float* __restrict__ root1,
                       f16* __restrict__ Wt, int PW) {
  int row = blockIdx.x, k = threadIdx.x, q = blockIdx.y;
  float v = 0.f;
  if (row < 9 * PW) {
    int cb = row / PW, j = row - cb * PW;
    int col = q * PW + j;
    v = (cb < 8) ? wrel1[(size_t)cb * 16384 + k * 128 + col] : root1[k * 128 + col];
  }
  Wt[(size_t)q * WTELEM + (size_t)row * 128 + k] = (f16)v;
}

// layer-2 concat weights, transposed: Wc[c][r*128+k] = wrel2[r][k][c]; [c][1024+k] = root2[k][c]
__global__ void k_tpwc2(const float* __restrict__ wrel2, const float* __restrict__ root2,
                        f16* __restrict__ Wc) {
  int c = blockIdx.x, k = threadIdx.x;
#pragma unroll
  for (int r = 0; r < 8; r++)
    Wc[(size_t)c * 1152 + r * 128 + k] = (f16)wrel2[(size_t)r * 16384 + k * 128 + c];
  Wc[(size_t)c * 1152 + 1024 + k] = (f16)root2[(size_t)k * 128 + c];
}

// ---------------- layer-1 GEMM: Y[9][M][PW] = blocked(A[M x 128] * Bt^T) --------
template <typename AT>
__global__ __launch_bounds__(256) void k_gemm3(const AT* __restrict__ A,
                                               const f16* __restrict__ Bt,
                                               f16* __restrict__ Y, int M, int ncol) {
  __shared__ f16 As[128 * 136];
  int tid = threadIdx.x;
  int m0 = blockIdx.x * 128;
  int PW = ncol / 9;
  int cbs = (PW == 64) ? 6 : 5;
#pragma unroll
  for (int cch = 0; cch < 8; cch++) {
    int ci = tid + cch * 256;
    int row = ci >> 4, c8 = ci & 15;
    int gm = m0 + row;
    f16x8 va = {};
    if (gm < M) {
      if constexpr (sizeof(AT) == 2) {
        va = *(const f16x8*)((const f16*)A + (size_t)gm * 128 + c8 * 8);
      } else {
        const float4* ap = (const float4*)((const float*)A + (size_t)gm * 128);
        float4 u0 = ap[c8 * 2], u1 = ap[c8 * 2 + 1];
        va[0] = (f16)u0.x; va[1] = (f16)u0.y; va[2] = (f16)u0.z; va[3] = (f16)u0.w;
        va[4] = (f16)u1.x; va[5] = (f16)u1.y; va[6] = (f16)u1.z; va[7] = (f16)u1.w;
      }
    }
    *(f16x8*)(As + row * 136 + c8 * 8) = va;
  }
  __syncthreads();
  int wid = tid >> 6, lane = tid & 63;
  int wm = (wid & 1) * 64, wn = (wid >> 1) * 64;
  int lm = lane & 15, lk = lane >> 4;
  f16x8 af[4][4];
#pragma unroll
  for (int ks = 0; ks < 4; ks++)
#pragma unroll
    for (int i = 0; i < 4; i++)
      af[ks][i] = *(const f16x8*)(As + (wm + i * 16 + lm) * 136 + ks * 32 + lk * 8);
  __syncthreads();
  f16* H = As;
  int NT = (ncol + 127) >> 7;
  for (int nt = blockIdx.y; nt < NT; nt += gridDim.y) {
    int n0 = nt * 128;
    f32x4 acc[4][4] = {};
#pragma unroll
    for (int ks = 0; ks < 4; ks++) {
      f16x8 b[4];
#pragma unroll
      for (int j = 0; j < 4; j++)
        b[j] = *(const f16x8*)(Bt + (size_t)(n0 + wn + j * 16 + lm) * 128 + ks * 32 + lk * 8);
#pragma unroll
      for (int i = 0; i < 4; i++)
#pragma unroll
        for (int j = 0; j < 4; j++)
          acc[i][j] = __builtin_amdgcn_mfma_f32_16x16x32_f16(b[j], af[ks][i], acc[i][j], 0, 0, 0);
    }
#pragma unroll
    for (int i = 0; i < 4; i++)
#pragma unroll
      for (int j = 0; j < 4; j++) {
        f16x4 o;
        o[0] = (f16)acc[i][j][0]; o[1] = (f16)acc[i][j][1];
        o[2] = (f16)acc[i][j][2]; o[3] = (f16)acc[i][j][3];
        *(f16x4*)(H + (wm + i * 16 + lm) * 136 + wn + j * 16 + lk * 4) = o;
      }
    __syncthreads();
    for (int i = tid; i < 128 * 16; i += 256) {
      int row = i >> 4, c8 = i & 15;
      int gm = m0 + row;
      int gc = n0 + c8 * 8;
      if (gm < M && gc < ncol) {
        int cb = gc >> cbs, wi = gc & (PW - 1);
        *(f16x8*)(Y + ((size_t)cb * M + gm) * PW + wi) =
            *(const f16x8*)(H + row * 136 + c8 * 8);
      }
    }
    __syncthreads();
  }
}

// ---------------- layer-1 edge aggregation (Y blocked [9][N][PW]) ----------------
// 16-lane subgroups; 4-deep edge unroll for load-latency hiding.
template <int PW>
__global__ __launch_bounds__(256) void k_edge_v(
    const f16* __restrict__ Y, const int* __restrict__ sps,
    const int* __restrict__ off, const float* __restrict__ sinvp,
    const float* __restrict__ bias, f16* __restrict__ hout, int N, int pass) {
  constexpr int CPL = PW / 16;
  int t = threadIdx.x;
  int g = t >> 4, st = t & 15;
  int n = blockIdx.x * 16 + g;
  if (n >= N) return;
  float sv = (st < 8) ? sinvp[n * 8 + st] : 0.f;
  int e0 = off[n], e1 = off[n + 1];
  float a[CPL], b2[CPL];
  {
    const f16* rp = Y + ((size_t)8 * N + n) * PW + st * CPL;
    const float* bp = bias + pass * PW + st * CPL;
#pragma unroll
    for (int q = 0; q < CPL; q++) { a[q] = (float)rp[q] + bp[q]; b2[q] = 0.f; }
  }
  int sgbase = t & 48;
  int e = e0;
  if constexpr (PW == 64) {
    for (; e + 3 < e1; e += 4) {
      int p0 = sps[e], p1 = sps[e + 1], p2 = sps[e + 2], p3 = sps[e + 3];
      int s0 = p0 & 0xFFFFF, ty0 = ((unsigned)p0) >> 20;
      int s1 = p1 & 0xFFFFF, ty1 = ((unsigned)p1) >> 20;
      int s2 = p2 & 0xFFFFF, ty2 = ((unsigned)p2) >> 20;
      int s3 = p3 & 0xFFFFF, ty3 = ((unsigned)p3) >> 20;
      f16x4 v0 = *(const f16x4*)(Y + ((size_t)ty0 * N + s0) * PW + st * 4);
      f16x4 v1 = *(const f16x4*)(Y + ((size_t)ty1 * N + s1) * PW + st * 4);
      f16x4 v2 = *(const f16x4*)(Y + ((size_t)ty2 * N + s2) * PW + st * 4);
      f16x4 v3 = *(const f16x4*)(Y + ((size_t)ty3 * N + s3) * PW + st * 4);
      float sc0 = __shfl(sv, sgbase | ty0);
      float sc1 = __shfl(sv, sgbase | ty1);
      float sc2 = __shfl(sv, sgbase | ty2);
      float sc3 = __shfl(sv, sgbase | ty3);
#pragma unroll
      for (int q = 0; q < 4; q++) {
        a[q]  += (float)v0[q] * sc0 + (float)v2[q] * sc2;
        b2[q] += (float)v1[q] * sc1 + (float)v3[q] * sc3;
      }
    }
    for (; e < e1; e++) {
      int p0 = sps[e];
      int s0 = p0 & 0xFFFFF, ty0 = ((unsigned)p0) >> 20;
      float sc0 = __shfl(sv, sgbase | ty0);
      f16x4 v0 = *(const f16x4*)(Y + ((size_t)ty0 * N + s0) * PW + st * 4);
#pragma unroll
      for (int q = 0; q < 4; q++) a[q] += (float)v0[q] * sc0;
    }
    f16x4 o;
#pragma unroll
    for (int q = 0; q < 4; q++) o[q] = (f16)fmaxf(a[q] + b2[q], 0.f);
    *(f16x4*)(hout + (size_t)n * 128 + pass * PW + st * 4) = o;
  } else {
    for (; e + 3 < e1; e += 4) {
      int p0 = sps[e], p1 = sps[e + 1], p2 = sps[e + 2], p3 = sps[e + 3];
      int s0 = p0 & 0xFFFFF, ty0 = ((unsigned)p0) >> 20;
      int s1 = p1 & 0xFFFFF, ty1 = ((unsigned)p1) >> 20;
      int s2 = p2 & 0xFFFFF, ty2 = ((unsigned)p2) >> 20;
      int s3 = p3 & 0xFFFFF, ty3 = ((unsigned)p3) >> 20;
      f16x2 v0 = *(const f16x2*)(Y + ((size_t)ty0 * N + s0) * PW + st * 2);
      f16x2 v1 = *(const f16x2*)(Y + ((size_t)ty1 * N + s1) * PW + st * 2);
      f16x2 v2 = *(const f16x2*)(Y + ((size_t)ty2 * N + s2) * PW + st * 2);
      f16x2 v3 = *(const f16x2*)(Y + ((size_t)ty3 * N + s3) * PW + st * 2);
      float sc0 = __shfl(sv, sgbase | ty0);
      float sc1 = __shfl(sv, sgbase | ty1);
      float sc2 = __shfl(sv, sgbase | ty2);
      float sc3 = __shfl(sv, sgbase | ty3);
#pragma unroll
      for (int q = 0; q < 2; q++) {
        a[q]  += (float)v0[q] * sc0 + (float)v2[q] * sc2;
        b2[q] += (float)v1[q] * sc1 + (float)v3[q] * sc3;
      }
    }
    for (; e < e1; e++) {
      int p0 = sps[e];
      int s0 = p0 & 0xFFFFF, ty0 = ((unsigned)p0) >> 20;
      float sc0 = __shfl(sv, sgbase | ty0);
      f16x2 v0 = *(const f16x2*)(Y + ((size_t)ty0 * N + s0) * PW + st * 2);
#pragma unroll
      for (int q = 0; q < 2; q++) a[q] += (float)v0[q] * sc0;
    }
    f16x2 o;
#pragma unroll
    for (int q = 0; q < 2; q++) o[q] = (f16)fmaxf(a[q] + b2[q], 0.f);
    *(f16x2*)(hout + (size_t)n * 128 + pass * PW + st * 2) = o;
  }
}

// ---------------- layer-2 aggregate-first: per-marked-node relation means --------
__global__ __launch_bounds__(128) void k_agg2(
    const f16* __restrict__ h1, const int* __restrict__ sps,
    const int* __restrict__ off, const float* __restrict__ sinvp,
    const int* __restrict__ mlist, const int* __restrict__ nm_p,
    f16* __restrict__ Mc, int cap) {
  int nm = *nm_p; if (nm > cap) nm = cap;
  int t = threadIdx.x;
  for (int i = blockIdx.x; i < nm; i += gridDim.x) {
    int n = mlist[i];
    int e0 = off[n], e1 = off[n + 1];
    float acc[8];
#pragma unroll
    for (int r = 0; r < 8; r++) acc[r] = 0.f;
    int e = e0;
    for (; e + 3 < e1; e += 4) {
      int p0 = sps[e], p1 = sps[e + 1], p2 = sps[e + 2], p3 = sps[e + 3];
      float v0 = (float)h1[(size_t)(p0 & 0xFFFFF) * 128 + t];
      float v1 = (float)h1[(size_t)(p1 & 0xFFFFF) * 128 + t];
      float v2 = (float)h1[(size_t)(p2 & 0xFFFFF) * 128 + t];
      float v3 = (float)h1[(size_t)(p3 & 0xFFFFF) * 128 + t];
      int ty0 = ((unsigned)p0) >> 20, ty1 = ((unsigned)p1) >> 20;
      int ty2 = ((unsigned)p2) >> 20, ty3 = ((unsigned)p3) >> 20;
#pragma unroll
      for (int r = 0; r < 8; r++) {
        acc[r] += (ty0 == r) ? v0 : 0.f;
        acc[r] += (ty1 == r) ? v1 : 0.f;
        acc[r] += (ty2 == r) ? v2 : 0.f;
        acc[r] += (ty3 == r) ? v3 : 0.f;
      }
    }
    for (; e < e1; e++) {
      int p0 = sps[e];
      float v0 = (float)h1[(size_t)(p0 & 0xFFFFF) * 128 + t];
      int ty0 = ((unsigned)p0) >> 20;
#pragma unroll
      for (int r = 0; r < 8; r++) acc[r] += (ty0 == r) ? v0 : 0.f;
    }
    f16* mp = Mc + (size_t)i * 1152;
#pragma unroll
    for (int r = 0; r < 8; r++)
      mp[r * 128 + t] = (f16)(acc[r] * sinvp[(size_t)n * 8 + r]);
    mp[1024 + t] = h1[(size_t)n * 128 + t];
  }
}

// ---------------- compact layer-2 GEMM: h2c = relu(Mc[nm x 1152] @ Wc^T + b2) ----
__global__ __launch_bounds__(256) void k_gemm_c(const f16* __restrict__ Mc,
                                                const f16* __restrict__ Wc,
                                                const float* __restrict__ bias,
                                                const int* __restrict__ nm_p,
                                                f16* __restrict__ h2c, int cap) {
  int nm = *nm_p; if (nm > cap) nm = cap;
  int m0 = blockIdx.x * 128;
  if (m0 >= nm) return;
  __shared__ f16 As[128 * 136];
  int tid = threadIdx.x;
  int wid = tid >> 6, lane = tid & 63;
  int wm = (wid & 1) * 64, wn = (wid >> 1) * 64;
  int lm = lane & 15, lk = lane >> 4;
  f32x4 acc[4][4] = {};
  for (int kc = 0; kc < 9; kc++) {
    __syncthreads();
#pragma unroll
    for (int cch = 0; cch < 8; cch++) {
      int ci = tid + cch * 256;
      int row = ci >> 4, c8 = ci & 15;
      int gm = m0 + row;
      f16x8 va = {};
      if (gm < nm) va = *(const f16x8*)(Mc + (size_t)gm * 1152 + kc * 128 + c8 * 8);
      *(f16x8*)(As + row * 136 + c8 * 8) = va;
    }
    __syncthreads();
#pragma unroll
    for (int ks = 0; ks < 4; ks++) {
      f16x8 a[4], b[4];
#pragma unroll
      for (int j = 0; j < 4; j++)
        b[j] = *(const f16x8*)(Wc + (size_t)(wn + j * 16 + lm) * 1152 + kc * 128 + ks * 32 + lk * 8);
#pragma unroll
      for (int i = 0; i < 4; i++)
        a[i] = *(const f16x8*)(As + (wm + i * 16 + lm) * 136 + ks * 32 + lk * 8);
#pragma unroll
      for (int i = 0; i < 4; i++)
#pragma unroll
        for (int j = 0; j < 4; j++)
          acc[i][j] = __builtin_amdgcn_mfma_f32_16x16x32_f16(b[j], a[i], acc[i][j], 0, 0, 0);
    }
  }
  __syncthreads();
  f16* H = As;
#pragma unroll
  for (int i = 0; i < 4; i++)
#pragma unroll
    for (int j = 0; j < 4; j++) {
      f16x4 o;
#pragma unroll
      for (int q = 0; q < 4; q++)
        o[q] = (f16)fmaxf(acc[i][j][q] + bias[wn + j * 16 + lk * 4 + q], 0.f);
      *(f16x4*)(H + (wm + i * 16 + lm) * 136 + wn + j * 16 + lk * 4) = o;
    }
  __syncthreads();
  for (int i = tid; i < 128 * 16; i += 256) {
    int row = i >> 4, c8 = i & 15;
    int gm = m0 + row;
    if (gm < nm)
      *(f16x8*)(h2c + (size_t)gm * 128 + c8 * 8) = *(const f16x8*)(H + row * 136 + c8 * 8);
  }
}

// ---------------- layer 3: root rows only, h2c via midx, weights in LDS ----------
__global__ __launch_bounds__(128) void k_layer3c(const f16* __restrict__ h2c,
                                                 const int* __restrict__ midx,
                                                 const int* __restrict__ sps,
                                                 const int* __restrict__ off,
                                                 const float* __restrict__ sinvp,
                                                 const int* __restrict__ ridx,
                                                 const float* __restrict__ wrel,
                                                 const float* __restrict__ wroot,
                                                 const float* __restrict__ b3,
                                                 float* __restrict__ out) {
  __shared__ f16 W[9 * 2048];
  __shared__ float red[2][16];
  __shared__ float sinv_s[8];
  int t = threadIdx.x;
  int n = ridx[blockIdx.x];
  for (int j = t; j < 9 * 2048; j += 128)
    W[j] = (f16)((j < 8 * 2048) ? wrel[j] : wroot[j - 8 * 2048]);
  if (t < 8) sinv_s[t] = sinvp[n * 8 + t];
  __syncthreads();
  int e0 = off[n], e1 = off[n + 1];
  int c = t & 15, kg = t >> 4;
  float a = 0.f;
  for (int e = e0; e < e1; e++) {
    int ps = sps[e];
    int s = ps & 0xFFFFF, ty = ((unsigned)ps) >> 20;
    int si = midx[s];
    float p = 0.f;
#pragma unroll
    for (int j = 0; j < 16; j++) {
      int k = kg * 16 + j;
      p += (float)h2c[(size_t)si * 128 + k] * (float)W[ty * 2048 + k * 16 + c];
    }
    a += sinv_s[ty] * p;
  }
  {
    int ni = midx[n];
    float p = 0.f;
#pragma unroll
    for (int j = 0; j < 16; j++) {
      int k = kg * 16 + j;
      p += (float)h2c[(size_t)ni * 128 + k] * (float)W[8 * 2048 + k * 16 + c];
    }
    a += p;
  }
  a += __shfl_xor(a, 16);
  a += __shfl_xor(a, 32);
  if ((t & 63) < 16) red[t >> 6][t & 15] = a;
  __syncthreads();
  if (t < 16) out[(size_t)blockIdx.x * 16 + t] = red[0][t] + red[1][t] + b3[t];
}

// ---------------- host ----------------
extern "C" void kernel_launch(void* const* d_in, const int* in_sizes, int n_in,
                              void* d_out, int out_size, void* d_ws, size_t ws_size,
                              hipStream_t stream) {
  const float* x     = (const float*)d_in[0];
  const int*   eidx  = (const int*)d_in[1];
  const int*   etyp  = (const int*)d_in[2];
  const int*   ridx  = (const int*)d_in[3];
  const float* wrel1 = (const float*)d_in[4];
  const float* root1 = (const float*)d_in[5];
  const float* b1    = (const float*)d_in[6];
  const float* wrel2 = (const float*)d_in[7];
  const float* root2 = (const float*)d_in[8];
  const float* b2    = (const float*)d_in[9];
  const float* wrel3 = (const float*)d_in[10];
  const float* root3 = (const float*)d_in[11];
  const float* b3    = (const float*)d_in[12];

  int N = in_sizes[0] / 128;
  int E = in_sizes[2];
  int NROOT = in_sizes[3];
  const int* esrc = eidx;
  const int* edst = eidx + E;

  char* p = (char*)d_ws;
  auto alloc = [&](size_t bytes) { void* r = (void*)p; p += (bytes + 255) & ~(size_t)255; return r; };
  int*   off   = (int*)alloc((size_t)(N + 1) * 4);
  int*   sps   = (int*)alloc((size_t)E * 4);
  f16*   h1    = (f16*)alloc((size_t)N * 128 * 2);
  f16*   h2c   = (f16*)alloc((size_t)N * 128 * 2);   // holds f16(x) for layer 1, then compact h2
  int*   mark  = (int*)alloc((size_t)N * 4);
  int*   midx  = (int*)alloc((size_t)N * 4);
  int*   mlist = (int*)alloc((size_t)N * 4);
  int*   nmv   = (int*)alloc(256);
  float* sinvp = (float*)alloc((size_t)N * 8 * 4);
  f16*   Wt    = (f16*)alloc((size_t)WTELEM * 2 * 4);
  f16*   Wc    = (f16*)alloc((size_t)128 * 1152 * 2);
  int*   bcnt  = (int*)alloc(512 * 4);
  int*   boff  = (int*)alloc(513 * 4);
  int*   bfill = (int*)alloc(512 * 4);

  size_t used = (size_t)(p - (char*)d_ws);
  size_t remain = ws_size > used ? ws_size - used : 0;
  int PW = (remain >= (size_t)N * 9 * 64 * 2 + (1u << 20)) ? 64 : 32;
  int ldy = 9 * PW;
  f16* Y = (f16*)alloc((size_t)N * ldy * 2);
  // setup scratch aliases Y (dead until first GEMM); Mc aliases Y (layer-2 phase)
  int* tmp  = (int*)Y;
  int* part = tmp + E;
  int* fill = part + 4096;
  f16* Mc   = Y;
  int  cap  = (int)(((size_t)N * ldy) / 1152);

  int nbuck = (N + 255) >> 8;
  int nbA = (E + ACHUNK - 1) / ACHUNK;
  int npass = 128 / PW;
  int NT = (ldy + 127) / 128;
  k_init<<<(N + 255) / 256, 256, 0, stream>>>(bcnt, bfill, nmv, mark, N);
  k_tpw4<<<dim3(NT * 128, npass), 128, 0, stream>>>(wrel1, root1, Wt, PW);
  k_tpwc2<<<128, 128, 0, stream>>>(wrel2, root2, Wc);
  // convert x -> f16 into h2c (dead until gemm_c writes it after layer-1 done)
  f16* xh = h2c;
  k_f32_to_f16<<<((N * 32) + 255) / 256, 256, 0, stream>>>(x, xh, N * 32);

  if (nbuck <= 512) {
    k_bhist<<<nbA, 256, 0, stream>>>(edst, E, bcnt, nbuck);
    k_bscan<<<1, 512, 0, stream>>>(bcnt, boff, nbuck);
    k_bucketA<<<nbA, 256, 0, stream>>>(esrc, edst, etyp, E, boff, bfill, tmp, nbuck);
    k_bucketB3<<<nbuck, 256, 0, stream>>>(tmp, boff, off, sps, sinvp, N);
    k_sentinel<<<1, 1, 0, stream>>>(off + N, E);
  } else {
    int eb = (E + 255) / 256;
    hipMemsetAsync(off, 0, (size_t)(N + 1) * 4, stream);
    hipMemsetAsync(fill, 0, (size_t)N * 4, stream);
    k_hist<<<eb, 256, 0, stream>>>(edst, E, off);
    int nb1 = (N + 4095) / 4096;
    k_scan1<<<nb1, 256, 0, stream>>>(off, off, part, N);
    k_scan2<<<1, 256, 0, stream>>>(part, nb1);
    k_scan3<<<(N + 255) / 256, 256, 0, stream>>>(off, part, N);
    k_sentinel<<<1, 1, 0, stream>>>(off + N, E);
    k_scatter<<<eb, 256, 0, stream>>>(esrc, edst, etyp, E, off, fill, sps);
    int ng16f = (N + 15) / 16;
    k_sinvp<<<ng16f, 256, 0, stream>>>(sps, off, sinvp, N);
  }
  k_mark<<<NROOT, 64, 0, stream>>>(ridx, off, sps, mark);
  k_compact<<<(N + 255) / 256, 256, 0, stream>>>(mark, midx, mlist, nmv, N);
  int ng16 = (N + 15) / 16;

  int mb = (N + 127) / 128;

  // layer 1: transform-first, A = f16(x)
  for (int ps = 0; ps < npass; ps++) {
    k_gemm3<f16><<<dim3(mb, 2), 256, 0, stream>>>(xh, Wt + (size_t)ps * WTELEM, Y, N, ldy);
    if (PW == 64)
      k_edge_v<64><<<ng16, 256, 0, stream>>>(Y, sps, off, sinvp, b1, h1, N, ps);
    else
      k_edge_v<32><<<ng16, 256, 0, stream>>>(Y, sps, off, sinvp, b1, h1, N, ps);
  }
  // layer 2: aggregate-first on marked nodes (Y region reused as Mc)
  k_agg2<<<2048, 128, 0, stream>>>(h1, sps, off, sinvp, mlist, nmv, Mc, cap);
  k_gemm_c<<<(cap + 127) / 128, 256, 0, stream>>>(Mc, Wc, b2, nmv, h2c, cap);
  // layer 3: roots only, compact h2
  k_layer3c<<<NROOT, 128, 0, stream>>>(h2c, midx, sps, off, sinvp, ridx, wrel3, root3,
                                       b3, (float*)d_out);
}